// Round 5
// baseline (409.398 us; speedup 1.0000x reference)
//
#include <hip/hip_runtime.h>

typedef __bf16 bf16x8 __attribute__((ext_vector_type(8)));
typedef float f32x4 __attribute__((ext_vector_type(4)));
typedef unsigned short u16x8 __attribute__((ext_vector_type(8)));

__device__ __forceinline__ unsigned short f2bf(float f) {
  unsigned int u = __builtin_bit_cast(unsigned int, f);
  u += 0x7FFFu + ((u >> 16) & 1u);           // round-to-nearest-even
  return (unsigned short)(u >> 16);
}

__device__ __forceinline__ void gload16(const void* g, void* l) {
  __builtin_amdgcn_global_load_lds((const __attribute__((address_space(1))) unsigned int*)g,
                                   (__attribute__((address_space(3))) unsigned int*)l,
                                   16, 0, 0);
}

// DPP row_ror reductions over 16-lane rows (VALU pipe, no LDS traffic)
template <int N>
__device__ __forceinline__ float rormax(float x) {
  int r = __builtin_amdgcn_update_dpp(0, __builtin_bit_cast(int, x), 0x120 + N, 0xF, 0xF, true);
  return fmaxf(x, __builtin_bit_cast(float, r));
}
template <int N>
__device__ __forceinline__ float rorsum(float x) {
  int r = __builtin_amdgcn_update_dpp(0, __builtin_bit_cast(int, x), 0x120 + N, 0xF, 0xF, true);
  return x + __builtin_bit_cast(float, r);
}
__device__ __forceinline__ float red16max(float x) {
  x = rormax<8>(x); x = rormax<4>(x); x = rormax<2>(x); return rormax<1>(x);
}
__device__ __forceinline__ float red16sum(float x) {
  x = rorsum<8>(x); x = rorsum<4>(x); x = rorsum<2>(x); return rorsum<1>(x);
}

// ---------------------------------------------------------------------------
// f32 -> bf16 conversion for {x, qkv_w, proj_w}
// ---------------------------------------------------------------------------
__global__ __launch_bounds__(256)
void cvt3_f32_bf16(const float* __restrict__ s0, unsigned short* __restrict__ d0, int n0,
                   const float* __restrict__ s1, unsigned short* __restrict__ d1, int n1,
                   const float* __restrict__ s2, unsigned short* __restrict__ d2)
{
  int blk = blockIdx.x;
  const float* s; unsigned short* d;
  if (blk < n0)            { s = s0; d = d0; }
  else if (blk < n0 + n1)  { s = s1; d = d1; blk -= n0; }
  else                     { s = s2; d = d2; blk -= n0 + n1; }
  const size_t e = ((size_t)blk * 256 + threadIdx.x) * 8;
  const float4 a = *(const float4*)(s + e);
  const float4 b = *(const float4*)(s + e + 4);
  u16x8 v;
  v[0] = f2bf(a.x); v[1] = f2bf(a.y); v[2] = f2bf(a.z); v[3] = f2bf(a.w);
  v[4] = f2bf(b.x); v[5] = f2bf(b.y); v[6] = f2bf(b.z); v[7] = f2bf(b.w);
  *(u16x8*)(d + e) = v;
}

// ---------------------------------------------------------------------------
// GEMM (m97 structure) + XCD-aware block swizzle (T1). Unchanged from R3.
// ---------------------------------------------------------------------------
template <bool OUTBF16>
__global__ __launch_bounds__(256, 2)
void gemm_bt16(const unsigned short* __restrict__ Ap, const unsigned short* __restrict__ Bp,
               void* __restrict__ Outp, int M, int N, int K)
{
  __shared__ __align__(16) char smA[128 * 128];
  __shared__ __align__(16) char smB[128 * 128];
  const int tid = threadIdx.x;
  const int wid = tid >> 6, lane = tid & 63;
  const int wr = wid >> 1, wc = wid & 1;
  const int lg = lane >> 4, lr = lane & 15;

  const int gx = gridDim.x;
  const int nwg = gx * gridDim.y;
  int bid = blockIdx.y * gx + blockIdx.x;
  bid = (bid & 7) * (nwg >> 3) + (bid >> 3);     // bijective: nwg % 8 == 0
  const int m0 = (bid / gx) * 128, n0 = (bid % gx) * 128;

  const int srow = wid * 8 + (lane >> 3);
  const int scol = (((lane & 7) ^ (lane >> 3)) << 3);
  const int lbase = wid * 1024;

  const f32x4 z4 = {0.f, 0.f, 0.f, 0.f};
  f32x4 acc[4][4];
#pragma unroll
  for (int i = 0; i < 4; ++i)
#pragma unroll
    for (int j = 0; j < 4; ++j) acc[i][j] = z4;

  for (int k0 = 0; k0 < K; k0 += 64) {
    __syncthreads();
#pragma unroll
    for (int c = 0; c < 4; ++c) {
      const int row = c * 32 + srow;
      gload16(Ap + (size_t)(m0 + row) * K + k0 + scol, smA + c * 4096 + lbase);
      gload16(Bp + (size_t)(n0 + row) * K + k0 + scol, smB + c * 4096 + lbase);
    }
    __syncthreads();
#pragma unroll
    for (int kk = 0; kk < 2; ++kk) {
      const int cb = (kk * 32 + lg * 8) * 2;
      bf16x8 af[4], bfr[4];
#pragma unroll
      for (int i = 0; i < 4; ++i) {
        const int row = wr * 64 + i * 16 + lr;
        af[i] = *(const bf16x8*)(smA + row * 128 + (cb ^ ((row & 7) << 4)));
      }
#pragma unroll
      for (int j = 0; j < 4; ++j) {
        const int row = wc * 64 + j * 16 + lr;
        bfr[j] = *(const bf16x8*)(smB + row * 128 + (cb ^ ((row & 7) << 4)));
      }
#pragma unroll
      for (int i = 0; i < 4; ++i)
#pragma unroll
        for (int j = 0; j < 4; ++j)
          acc[i][j] = __builtin_amdgcn_mfma_f32_16x16x32_bf16(af[i], bfr[j], acc[i][j], 0, 0, 0);
    }
  }
#pragma unroll
  for (int i = 0; i < 4; ++i)
#pragma unroll
    for (int j = 0; j < 4; ++j)
#pragma unroll
      for (int r = 0; r < 4; ++r) {
        const int row = m0 + wr * 64 + i * 16 + lg * 4 + r;
        const int col = n0 + wc * 64 + j * 16 + lr;
        const float val = acc[i][j][r];
        if (OUTBF16) ((unsigned short*)Outp)[(size_t)row * N + col] = f2bf(val);
        else         ((float*)Outp)[(size_t)row * N + col] = val;
      }
}

// ---------------------------------------------------------------------------
// Flash attention v4: QBLK=128 (two 64-row blocks per wave set), K/V
// reg-double-buffered, LDS V-transpose (proven R2 path), DPP softmax,
// kf/vf LDS reads shared across both row-blocks. LDS 48KB.
// ---------------------------------------------------------------------------
__global__ __launch_bounds__(256)
void attn_fwd(const unsigned short* __restrict__ qkv, unsigned short* __restrict__ outp)
{
  constexpr int T = 2048, ROWS = 6144;
  const int qt = (int)gridDim.x - 1 - (int)blockIdx.x;  // 0..15, heavy first
  const int bh = blockIdx.y;
  const int b = bh >> 4, h = bh & 15;
  const int q0 = qt * 128;
  const int tid = threadIdx.x;
  const int wid = tid >> 6, lane = tid & 63;
  const int lg = lane >> 4, lr = lane & 15;

  __shared__ __align__(16) char Ks[64 * 256];   // 16KB [64 k][128 d] swizzled
  __shared__ __align__(16) char Vt[128 * 128];  // 16KB [128 d][64 k] swizzled
  __shared__ __align__(16) char Sc[64 * 256];   // 16KB Vrow overlay / Ps[128][64]

  const int se_row[4] = {((0 * 256 + tid) * 8) >> 7, ((1 * 256 + tid) * 8) >> 7,
                         ((2 * 256 + tid) * 8) >> 7, ((3 * 256 + tid) * 8) >> 7};
  const int se_col = (tid * 8) & 127;

  // Q fragments for both row-blocks
  bf16x8 qf[2][4];
#pragma unroll
  for (int rb = 0; rb < 2; ++rb) {
    const size_t qrow = (size_t)(b * T + q0 + rb * 64 + wid * 16 + lr) * ROWS + h * 128;
#pragma unroll
    for (int kd = 0; kd < 4; ++kd)
      qf[rb][kd] = __builtin_bit_cast(bf16x8, *(const u16x8*)(qkv + qrow + kd * 32 + lg * 8));
  }

  const f32x4 z4 = {0.f, 0.f, 0.f, 0.f};
  f32x4 oacc[2][8];
#pragma unroll
  for (int rb = 0; rb < 2; ++rb)
#pragma unroll
    for (int jj = 0; jj < 8; ++jj) oacc[rb][jj] = z4;
  float mrow[2][4], lsum[2][4];
#pragma unroll
  for (int rb = 0; rb < 2; ++rb)
#pragma unroll
    for (int r = 0; r < 4; ++r) { mrow[rb][r] = -1e30f; lsum[rb][r] = 0.f; }
  const float scale = 0.08838834764831845f;   // 1/sqrt(128)

  const int NT = 2 * qt + 2;
  u16x8 kreg[4], vreg[4];
  {
    const int kbase = b * T;
#pragma unroll
    for (int r = 0; r < 4; ++r) {
      const size_t g = (size_t)(kbase + se_row[r]) * ROWS + h * 128 + se_col;
      kreg[r] = *(const u16x8*)(qkv + g + 2048);
      vreg[r] = *(const u16x8*)(qkv + g + 4096);
    }
  }

  for (int kt = 0; kt < NT; ++kt) {
    __syncthreads();   // A: prev tile's LDS readers done
#pragma unroll
    for (int r = 0; r < 4; ++r) {
      const int row = se_row[r];
      const int sw = (se_col * 2) ^ ((row & 7) << 4);
      *(u16x8*)(Ks + row * 256 + sw) = kreg[r];
      *(u16x8*)(Sc + row * 256 + sw) = vreg[r];
    }
    __syncthreads();   // B: staging visible
    if (kt + 1 < NT) {
      const int nb = b * T + (kt + 1) * 64;
#pragma unroll
      for (int r = 0; r < 4; ++r) {
        const size_t g = (size_t)(nb + se_row[r]) * ROWS + h * 128 + se_col;
        kreg[r] = *(const u16x8*)(qkv + g + 2048);
        vreg[r] = *(const u16x8*)(qkv + g + 4096);
      }
    }

    // S = Q K^T for both row-blocks (kf read once, 2 MFMA)
    f32x4 sf[2][4];
#pragma unroll
    for (int rb = 0; rb < 2; ++rb)
#pragma unroll
      for (int j = 0; j < 4; ++j) sf[rb][j] = z4;
#pragma unroll
    for (int kd = 0; kd < 4; ++kd) {
      const int cb = (kd * 32 + lg * 8) * 2;
#pragma unroll
      for (int j = 0; j < 4; ++j) {
        const int row = j * 16 + lr;
        bf16x8 kf = *(const bf16x8*)(Ks + row * 256 + (cb ^ ((row & 7) << 4)));
        sf[0][j] = __builtin_amdgcn_mfma_f32_16x16x32_bf16(qf[0][kd], kf, sf[0][j], 0, 0, 0);
        sf[1][j] = __builtin_amdgcn_mfma_f32_16x16x32_bf16(qf[1][kd], kf, sf[1][j], 0, 0, 0);
      }
    }

    // V transpose: Sc(Vrow)[k][d] -> Vt[d][k] (scalar LDS reads, 2-way = free)
#pragma unroll
    for (int r2 = 0; r2 < 4; ++r2) {
      const int chunk = r2 * 256 + tid;
      const int d = chunk & 127, k0 = (chunk >> 7) * 8;
      u16x8 v;
#pragma unroll
      for (int i = 0; i < 8; ++i)
        v[i] = *(const unsigned short*)(Sc + (k0 + i) * 256 + ((d * 2) ^ (((k0 + i) & 7) << 4)));
      *(u16x8*)(Vt + d * 128 + ((k0 * 2) ^ ((d & 7) << 4))) = v;
    }

    // softmax per row-block (DPP reductions)
#pragma unroll
    for (int rb = 0; rb < 2; ++rb) {
      const bool maskneed = (kt >= 2 * qt + rb);
#pragma unroll
      for (int j = 0; j < 4; ++j)
#pragma unroll
        for (int r = 0; r < 4; ++r) {
          float s = sf[rb][j][r] * scale;
          const int key = kt * 64 + j * 16 + lr;
          const int qi  = q0 + rb * 64 + wid * 16 + lg * 4 + r;
          if (maskneed && key > qi) s = -1e30f;
          sf[rb][j][r] = s;
        }
      float alpha[4];
#pragma unroll
      for (int r = 0; r < 4; ++r) {
        const float pm = red16max(fmaxf(fmaxf(sf[rb][0][r], sf[rb][1][r]),
                                        fmaxf(sf[rb][2][r], sf[rb][3][r])));
        const float mn = fmaxf(mrow[rb][r], pm);
        alpha[r] = __expf(mrow[rb][r] - mn);
        mrow[rb][r] = mn;
      }
      float rs[4] = {0.f, 0.f, 0.f, 0.f};
#pragma unroll
      for (int j = 0; j < 4; ++j)
#pragma unroll
        for (int r = 0; r < 4; ++r) {
          const float p = __expf(sf[rb][j][r] - mrow[rb][r]);
          sf[rb][j][r] = p;
          rs[r] += p;
        }
#pragma unroll
      for (int r = 0; r < 4; ++r) lsum[rb][r] = lsum[rb][r] * alpha[r] + red16sum(rs[r]);
#pragma unroll
      for (int jj = 0; jj < 8; ++jj)
#pragma unroll
        for (int r = 0; r < 4; ++r) oacc[rb][jj][r] *= alpha[r];
    }

    __syncthreads();   // C: Vt complete; Sc(Vrow) reads done -> Ps may reuse Sc

    // P -> Ps[128][64] (wave-private rows)
#pragma unroll
    for (int rb = 0; rb < 2; ++rb)
#pragma unroll
      for (int j = 0; j < 4; ++j)
#pragma unroll
        for (int r = 0; r < 4; ++r) {
          const int prow = rb * 64 + wid * 16 + lg * 4 + r;
          const int pcol = j * 16 + lr;
          *(unsigned short*)(Sc + prow * 128 + ((pcol * 2) ^ ((prow & 7) << 4))) = f2bf(sf[rb][j][r]);
        }
    asm volatile("s_waitcnt lgkmcnt(0)" ::: "memory");
    __builtin_amdgcn_sched_barrier(0);

    // O += P V (vf read once per jj, 2 MFMA)
#pragma unroll
    for (int kk = 0; kk < 2; ++kk) {
      const int pcb = (kk * 32 + lg * 8) * 2;
      const int prow0 = wid * 16 + lr;
      const int prow1 = 64 + wid * 16 + lr;
      bf16x8 pf0 = *(const bf16x8*)(Sc + prow0 * 128 + (pcb ^ ((prow0 & 7) << 4)));
      bf16x8 pf1 = *(const bf16x8*)(Sc + prow1 * 128 + (pcb ^ ((prow1 & 7) << 4)));
#pragma unroll
      for (int jj = 0; jj < 8; ++jj) {
        const int vrow = jj * 16 + lr;
        bf16x8 vf = *(const bf16x8*)(Vt + vrow * 128 + (pcb ^ ((vrow & 7) << 4)));
        oacc[0][jj] = __builtin_amdgcn_mfma_f32_16x16x32_bf16(pf0, vf, oacc[0][jj], 0, 0, 0);
        oacc[1][jj] = __builtin_amdgcn_mfma_f32_16x16x32_bf16(pf1, vf, oacc[1][jj], 0, 0, 0);
      }
    }
  }

  // epilogue
#pragma unroll
  for (int rb = 0; rb < 2; ++rb)
#pragma unroll
    for (int jj = 0; jj < 8; ++jj)
#pragma unroll
      for (int r = 0; r < 4; ++r) {
        const int q = q0 + rb * 64 + wid * 16 + lg * 4 + r;
        const int col = h * 128 + jj * 16 + lr;
        const float o = oacc[rb][jj][r] / lsum[rb][r];
        outp[(size_t)(b * T + q) * 2048 + col] = f2bf(o);
      }
}

// ---------------------------------------------------------------------------
extern "C" void kernel_launch(void* const* d_in, const int* in_sizes, int n_in,
                              void* d_out, int out_size, void* d_ws, size_t ws_size,
                              hipStream_t stream) {
  (void)in_sizes; (void)n_in; (void)out_size; (void)ws_size;
  const float* x     = (const float*)d_in[0];   // [2,2048,2048]
  const float* qkvw  = (const float*)d_in[1];   // [6144,2048]
  const float* projw = (const float*)d_in[2];   // [2048,2048]

  unsigned short* qkvb   = (unsigned short*)d_ws;               // [4096][6144]
  unsigned short* attnb  = qkvb   + (size_t)4096 * 6144;        // [4096][2048]
  unsigned short* xb     = attnb  + (size_t)4096 * 2048;        // [4096][2048]
  unsigned short* qkvwb  = xb     + (size_t)4096 * 2048;        // [6144][2048]
  unsigned short* projwb = qkvwb  + (size_t)6144 * 2048;        // [2048][2048]
  float* out = (float*)d_out;                                   // [4096][2048] f32

  cvt3_f32_bf16<<<4096 + 6144 + 2048, 256, 0, stream>>>(
      x, xb, 4096, qkvw, qkvwb, 6144, projw, projwb);
  gemm_bt16<true><<<dim3(6144 / 128, 4096 / 128), 256, 0, stream>>>(
      xb, qkvwb, qkvb, 4096, 6144, 2048);
  attn_fwd<<<dim3(16, 32), 256, 0, stream>>>(qkvb, attnb);
  gemm_bt16<false><<<dim3(2048 / 128, 4096 / 128), 256, 0, stream>>>(
      attnb, projwb, out, 4096, 2048, 2048);
}

// Round 6
// 305.303 us; speedup vs baseline: 1.3410x; 1.3410x over previous
//
#include <hip/hip_runtime.h>

typedef __bf16 bf16x8 __attribute__((ext_vector_type(8)));
typedef float f32x4 __attribute__((ext_vector_type(4)));
typedef unsigned short u16x8 __attribute__((ext_vector_type(8)));

__device__ __forceinline__ unsigned short f2bf(float f) {
  unsigned int u = __builtin_bit_cast(unsigned int, f);
  u += 0x7FFFu + ((u >> 16) & 1u);           // round-to-nearest-even
  return (unsigned short)(u >> 16);
}

__device__ __forceinline__ void gload16(const void* g, void* l) {
  __builtin_amdgcn_global_load_lds((const __attribute__((address_space(1))) unsigned int*)g,
                                   (__attribute__((address_space(3))) unsigned int*)l,
                                   16, 0, 0);
}

// DPP row_ror reductions over 16-lane rows (VALU pipe, no LDS traffic)
template <int N>
__device__ __forceinline__ float rormax(float x) {
  int r = __builtin_amdgcn_update_dpp(0, __builtin_bit_cast(int, x), 0x120 + N, 0xF, 0xF, true);
  return fmaxf(x, __builtin_bit_cast(float, r));
}
template <int N>
__device__ __forceinline__ float rorsum(float x) {
  int r = __builtin_amdgcn_update_dpp(0, __builtin_bit_cast(int, x), 0x120 + N, 0xF, 0xF, true);
  return x + __builtin_bit_cast(float, r);
}
__device__ __forceinline__ float red16max(float x) {
  x = rormax<8>(x); x = rormax<4>(x); x = rormax<2>(x); return rormax<1>(x);
}
__device__ __forceinline__ float red16sum(float x) {
  x = rorsum<8>(x); x = rorsum<4>(x); x = rorsum<2>(x); return rorsum<1>(x);
}

// ---------------------------------------------------------------------------
// f32 -> bf16 conversion for {x, qkv_w, proj_w}
// ---------------------------------------------------------------------------
__global__ __launch_bounds__(256)
void cvt3_f32_bf16(const float* __restrict__ s0, unsigned short* __restrict__ d0, int n0,
                   const float* __restrict__ s1, unsigned short* __restrict__ d1, int n1,
                   const float* __restrict__ s2, unsigned short* __restrict__ d2)
{
  int blk = blockIdx.x;
  const float* s; unsigned short* d;
  if (blk < n0)            { s = s0; d = d0; }
  else if (blk < n0 + n1)  { s = s1; d = d1; blk -= n0; }
  else                     { s = s2; d = d2; blk -= n0 + n1; }
  const size_t e = ((size_t)blk * 256 + threadIdx.x) * 8;
  const float4 a = *(const float4*)(s + e);
  const float4 b = *(const float4*)(s + e + 4);
  u16x8 v;
  v[0] = f2bf(a.x); v[1] = f2bf(a.y); v[2] = f2bf(a.z); v[3] = f2bf(a.w);
  v[4] = f2bf(b.x); v[5] = f2bf(b.y); v[6] = f2bf(b.z); v[7] = f2bf(b.w);
  *(u16x8*)(d + e) = v;
}

// ---------------------------------------------------------------------------
// GEMM (m97 structure) + XCD-aware block swizzle (T1). Unchanged.
// ---------------------------------------------------------------------------
template <bool OUTBF16>
__global__ __launch_bounds__(256, 2)
void gemm_bt16(const unsigned short* __restrict__ Ap, const unsigned short* __restrict__ Bp,
               void* __restrict__ Outp, int M, int N, int K)
{
  __shared__ __align__(16) char smA[128 * 128];
  __shared__ __align__(16) char smB[128 * 128];
  const int tid = threadIdx.x;
  const int wid = tid >> 6, lane = tid & 63;
  const int wr = wid >> 1, wc = wid & 1;
  const int lg = lane >> 4, lr = lane & 15;

  const int gx = gridDim.x;
  const int nwg = gx * gridDim.y;
  int bid = blockIdx.y * gx + blockIdx.x;
  bid = (bid & 7) * (nwg >> 3) + (bid >> 3);     // bijective: nwg % 8 == 0
  const int m0 = (bid / gx) * 128, n0 = (bid % gx) * 128;

  const int srow = wid * 8 + (lane >> 3);
  const int scol = (((lane & 7) ^ (lane >> 3)) << 3);
  const int lbase = wid * 1024;

  const f32x4 z4 = {0.f, 0.f, 0.f, 0.f};
  f32x4 acc[4][4];
#pragma unroll
  for (int i = 0; i < 4; ++i)
#pragma unroll
    for (int j = 0; j < 4; ++j) acc[i][j] = z4;

  for (int k0 = 0; k0 < K; k0 += 64) {
    __syncthreads();
#pragma unroll
    for (int c = 0; c < 4; ++c) {
      const int row = c * 32 + srow;
      gload16(Ap + (size_t)(m0 + row) * K + k0 + scol, smA + c * 4096 + lbase);
      gload16(Bp + (size_t)(n0 + row) * K + k0 + scol, smB + c * 4096 + lbase);
    }
    __syncthreads();
#pragma unroll
    for (int kk = 0; kk < 2; ++kk) {
      const int cb = (kk * 32 + lg * 8) * 2;
      bf16x8 af[4], bfr[4];
#pragma unroll
      for (int i = 0; i < 4; ++i) {
        const int row = wr * 64 + i * 16 + lr;
        af[i] = *(const bf16x8*)(smA + row * 128 + (cb ^ ((row & 7) << 4)));
      }
#pragma unroll
      for (int j = 0; j < 4; ++j) {
        const int row = wc * 64 + j * 16 + lr;
        bfr[j] = *(const bf16x8*)(smB + row * 128 + (cb ^ ((row & 7) << 4)));
      }
#pragma unroll
      for (int i = 0; i < 4; ++i)
#pragma unroll
        for (int j = 0; j < 4; ++j)
          acc[i][j] = __builtin_amdgcn_mfma_f32_16x16x32_bf16(af[i], bfr[j], acc[i][j], 0, 0, 0);
    }
  }
#pragma unroll
  for (int i = 0; i < 4; ++i)
#pragma unroll
    for (int j = 0; j < 4; ++j)
#pragma unroll
      for (int r = 0; r < 4; ++r) {
        const int row = m0 + wr * 64 + i * 16 + lg * 4 + r;
        const int col = n0 + wc * 64 + j * 16 + lr;
        const float val = acc[i][j][r];
        if (OUTBF16) ((unsigned short*)Outp)[(size_t)row * N + col] = f2bf(val);
        else         ((float*)Outp)[(size_t)row * N + col] = val;
      }
}

// ---------------------------------------------------------------------------
// V transpose: qkv V-part [b*T+t][4096 + h*128 + d] -> vT[(bh*128+d)*2048 + t]
// One block per (bh, 64-row t-tile). LDS round-trip, coalesced both sides.
// ---------------------------------------------------------------------------
__global__ __launch_bounds__(256)
void vtrans(const unsigned short* __restrict__ qkv, unsigned short* __restrict__ vT)
{
  constexpr int T = 2048, ROWS = 6144;
  const int bh = blockIdx.y, b = bh >> 4, h = bh & 15;
  const int t0 = blockIdx.x * 64;
  const int tid = threadIdx.x;
  __shared__ __align__(16) char Sc[64 * 256];   // [t][d] swizzled

#pragma unroll
  for (int c = 0; c < 4; ++c) {
    const int row = c * 16 + (tid >> 4);        // t index
    const int col = (tid & 15) * 8;             // d
    u16x8 v = *(const u16x8*)(qkv + (size_t)(b * T + t0 + row) * ROWS + 4096 + h * 128 + col);
    *(u16x8*)(Sc + row * 256 + ((col * 2) ^ ((row & 7) << 4))) = v;
  }
  __syncthreads();
#pragma unroll
  for (int c = 0; c < 4; ++c) {
    const int d = c * 32 + (tid >> 3);
    const int t = (tid & 7) * 8;
    u16x8 v;
#pragma unroll
    for (int i = 0; i < 8; ++i)
      v[i] = *(const unsigned short*)(Sc + (t + i) * 256 + ((d * 2) ^ (((t + i) & 7) << 4)));
    *(u16x8*)(vT + ((size_t)bh * 128 + d) * 2048 + t0 + t) = v;
  }
}

// ---------------------------------------------------------------------------
// Flash attention v5: K and V^T tiles staged via width-16 global_load_lds
// (linear LDS dest + inverse-swizzled source), single-buffered; DPP softmax;
// Ps separate 8KB. LDS 40KB -> 4 blocks/CU; VGPR capped for 4 waves/SIMD.
// ---------------------------------------------------------------------------
__global__ __launch_bounds__(256, 4)
void attn_fwd(const unsigned short* __restrict__ qkv, const unsigned short* __restrict__ vT,
              unsigned short* __restrict__ outp)
{
  constexpr int T = 2048, ROWS = 6144;
  const int qt = (int)gridDim.x - 1 - (int)blockIdx.x;  // heavy tiles first
  const int bh = blockIdx.y;
  const int b = bh >> 4, h = bh & 15;
  const int q0 = qt * 64;
  const int tid = threadIdx.x;
  const int wid = tid >> 6, lane = tid & 63;
  const int lg = lane >> 4, lr = lane & 15;

  __shared__ __align__(16) char Ks[64 * 256];   // 16KB [64 k][128 d] swizzled
  __shared__ __align__(16) char Vt[128 * 128];  // 16KB [128 d][64 k] swizzled
  __shared__ __align__(16) char Ps[64 * 128];   // 8KB  [64 q][64 k] swizzled

  // K staging: rows 256B. round c: row = c*16 + wid*4 + (lane>>4), slot = lane&15,
  // source col = (slot ^ (row&7))*8 ; LDS dest wave-uniform base, HW adds lane*16.
  const int krow = wid * 4 + (lane >> 4);                       // + c*16
  const int kcol = (((lane & 15) ^ (krow & 7)) << 3);           // row&7 == krow&7
  // V staging: rows 128B. round c: row = c*32 + wid*8 + (lane>>3), slot = lane&7.
  const int vrow_s = wid * 8 + (lane >> 3);                     // + c*32 (c*32 doesn't affect &7)
  const int vcol_s = (((lane & 7) ^ (vrow_s & 7)) << 3);

  // Q fragments hoisted to registers
  const size_t qrow = (size_t)(b * T + q0 + wid * 16 + lr) * ROWS + h * 128;
  bf16x8 qf[4];
#pragma unroll
  for (int kd = 0; kd < 4; ++kd)
    qf[kd] = __builtin_bit_cast(bf16x8, *(const u16x8*)(qkv + qrow + kd * 32 + lg * 8));

  const f32x4 z4 = {0.f, 0.f, 0.f, 0.f};
  f32x4 oacc[8];
#pragma unroll
  for (int jj = 0; jj < 8; ++jj) oacc[jj] = z4;
  float mrow[4] = {-1e30f, -1e30f, -1e30f, -1e30f};
  float lsum[4] = {0.f, 0.f, 0.f, 0.f};
  const float scale = 0.08838834764831845f;   // 1/sqrt(128)

  for (int kt = 0; kt <= qt; ++kt) {
    const int kbase = b * T + kt * 64;
    __syncthreads();   // previous tile's LDS readers done
    // stage K tile + V^T tile via async global->LDS
#pragma unroll
    for (int c = 0; c < 4; ++c) {
      gload16(qkv + (size_t)(kbase + c * 16 + krow) * ROWS + 2048 + h * 128 + kcol,
              Ks + c * 4096 + wid * 1024);
      gload16(vT + ((size_t)bh * 128 + c * 32 + vrow_s) * 2048 + kt * 64 + vcol_s,
              Vt + c * 4096 + wid * 1024);
    }
    asm volatile("s_waitcnt vmcnt(0)" ::: "memory");
    __syncthreads();   // all waves' tiles resident

    // S = Q K^T
    f32x4 sf[4];
#pragma unroll
    for (int j = 0; j < 4; ++j) sf[j] = z4;
#pragma unroll
    for (int kd = 0; kd < 4; ++kd) {
      const int cb = (kd * 32 + lg * 8) * 2;
#pragma unroll
      for (int j = 0; j < 4; ++j) {
        const int row = j * 16 + lr;
        bf16x8 kf = *(const bf16x8*)(Ks + row * 256 + (cb ^ ((row & 7) << 4)));
        sf[j] = __builtin_amdgcn_mfma_f32_16x16x32_bf16(qf[kd], kf, sf[j], 0, 0, 0);
      }
    }

    // softmax (DPP reductions, VALU only)
    const bool diag = (kt == qt);
#pragma unroll
    for (int j = 0; j < 4; ++j)
#pragma unroll
      for (int r = 0; r < 4; ++r) {
        float s = sf[j][r] * scale;
        if (diag && (j * 16 + lr > wid * 16 + lg * 4 + r)) s = -1e30f;
        sf[j][r] = s;
      }
    float alpha[4];
#pragma unroll
    for (int r = 0; r < 4; ++r) {
      const float pm = red16max(fmaxf(fmaxf(sf[0][r], sf[1][r]), fmaxf(sf[2][r], sf[3][r])));
      const float mn = fmaxf(mrow[r], pm);
      alpha[r] = __expf(mrow[r] - mn);
      mrow[r] = mn;
    }
    float rs[4] = {0.f, 0.f, 0.f, 0.f};
#pragma unroll
    for (int j = 0; j < 4; ++j)
#pragma unroll
      for (int r = 0; r < 4; ++r) {
        const float p = __expf(sf[j][r] - mrow[r]);
        sf[j][r] = p;
        rs[r] += p;
      }
#pragma unroll
    for (int r = 0; r < 4; ++r) lsum[r] = lsum[r] * alpha[r] + red16sum(rs[r]);

    // P -> Ps (wave-private rows)
#pragma unroll
    for (int j = 0; j < 4; ++j)
#pragma unroll
      for (int r = 0; r < 4; ++r) {
        const int prow = wid * 16 + lg * 4 + r;
        const int pcol = j * 16 + lr;
        *(unsigned short*)(Ps + prow * 128 + ((pcol * 2) ^ ((prow & 7) << 4))) = f2bf(sf[j][r]);
      }
    // O rescale (VALU, covers P-write latency)
#pragma unroll
    for (int jj = 0; jj < 8; ++jj)
#pragma unroll
      for (int r = 0; r < 4; ++r) oacc[jj][r] *= alpha[r];
    // same-wave DS ordering (rule #18)
    asm volatile("s_waitcnt lgkmcnt(0)" ::: "memory");
    __builtin_amdgcn_sched_barrier(0);

    // O += P V
#pragma unroll
    for (int kk = 0; kk < 2; ++kk) {
      const int prow = wid * 16 + lr;
      const int pcb = (kk * 32 + lg * 8) * 2;
      bf16x8 pf = *(const bf16x8*)(Ps + prow * 128 + (pcb ^ ((prow & 7) << 4)));
#pragma unroll
      for (int jj = 0; jj < 8; ++jj) {
        const int vrow = jj * 16 + lr;
        bf16x8 vf = *(const bf16x8*)(Vt + vrow * 128 + (pcb ^ ((vrow & 7) << 4)));
        oacc[jj] = __builtin_amdgcn_mfma_f32_16x16x32_bf16(pf, vf, oacc[jj], 0, 0, 0);
      }
    }
  }

  // epilogue
#pragma unroll
  for (int jj = 0; jj < 8; ++jj)
#pragma unroll
    for (int r = 0; r < 4; ++r) {
      const int q = q0 + wid * 16 + lg * 4 + r;
      const int col = h * 128 + jj * 16 + lr;
      const float o = oacc[jj][r] / lsum[r];
      outp[(size_t)(b * T + q) * 2048 + col] = f2bf(o);
    }
}

// ---------------------------------------------------------------------------
extern "C" void kernel_launch(void* const* d_in, const int* in_sizes, int n_in,
                              void* d_out, int out_size, void* d_ws, size_t ws_size,
                              hipStream_t stream) {
  (void)in_sizes; (void)n_in; (void)out_size; (void)ws_size;
  const float* x     = (const float*)d_in[0];   // [2,2048,2048]
  const float* qkvw  = (const float*)d_in[1];   // [6144,2048]
  const float* projw = (const float*)d_in[2];   // [2048,2048]

  unsigned short* qkvb   = (unsigned short*)d_ws;               // [4096][6144]
  unsigned short* attnb  = qkvb   + (size_t)4096 * 6144;        // [4096][2048]
  unsigned short* xb     = attnb  + (size_t)4096 * 2048;        // [4096][2048]
  unsigned short* qkvwb  = xb     + (size_t)4096 * 2048;        // [6144][2048]
  unsigned short* projwb = qkvwb  + (size_t)6144 * 2048;        // [2048][2048]
  // vT overlays xb: xb is dead after gemm1, vtrans runs after gemm1 (stream order)
  unsigned short* vT     = xb;                                  // [32*128][2048]
  float* out = (float*)d_out;                                   // [4096][2048] f32

  cvt3_f32_bf16<<<4096 + 6144 + 2048, 256, 0, stream>>>(
      x, xb, 4096, qkvw, qkvwb, 6144, projw, projwb);
  gemm_bt16<true><<<dim3(6144 / 128, 4096 / 128), 256, 0, stream>>>(
      xb, qkvwb, qkvb, 4096, 6144, 2048);
  vtrans<<<dim3(32, 32), 256, 0, stream>>>(qkvb, vT);
  attn_fwd<<<dim3(32, 32), 256, 0, stream>>>(qkvb, vT, attnb);
  gemm_bt16<false><<<dim3(2048 / 128, 4096 / 128), 256, 0, stream>>>(
      attnb, projwb, out, 4096, 2048, 2048);
}

// Round 7
// 298.376 us; speedup vs baseline: 1.3721x; 1.0232x over previous
//
#include <hip/hip_runtime.h>

typedef __bf16 bf16x8 __attribute__((ext_vector_type(8)));
typedef float f32x4 __attribute__((ext_vector_type(4)));
typedef unsigned short u16x8 __attribute__((ext_vector_type(8)));

__device__ __forceinline__ unsigned short f2bf(float f) {
  unsigned int u = __builtin_bit_cast(unsigned int, f);
  u += 0x7FFFu + ((u >> 16) & 1u);           // round-to-nearest-even
  return (unsigned short)(u >> 16);
}

__device__ __forceinline__ void gload16(const void* g, void* l) {
  __builtin_amdgcn_global_load_lds((const __attribute__((address_space(1))) unsigned int*)g,
                                   (__attribute__((address_space(3))) unsigned int*)l,
                                   16, 0, 0);
}

// DPP row_ror reductions over 16-lane rows (VALU pipe, no LDS traffic)
template <int N>
__device__ __forceinline__ float rormax(float x) {
  int r = __builtin_amdgcn_update_dpp(0, __builtin_bit_cast(int, x), 0x120 + N, 0xF, 0xF, true);
  return fmaxf(x, __builtin_bit_cast(float, r));
}
template <int N>
__device__ __forceinline__ float rorsum(float x) {
  int r = __builtin_amdgcn_update_dpp(0, __builtin_bit_cast(int, x), 0x120 + N, 0xF, 0xF, true);
  return x + __builtin_bit_cast(float, r);
}
__device__ __forceinline__ float red16max(float x) {
  x = rormax<8>(x); x = rormax<4>(x); x = rormax<2>(x); return rormax<1>(x);
}
__device__ __forceinline__ float red16sum(float x) {
  x = rorsum<8>(x); x = rorsum<4>(x); x = rorsum<2>(x); return rorsum<1>(x);
}

// ---------------------------------------------------------------------------
// f32 -> bf16 conversion for {x, qkv_w, proj_w}
// ---------------------------------------------------------------------------
__global__ __launch_bounds__(256)
void cvt3_f32_bf16(const float* __restrict__ s0, unsigned short* __restrict__ d0, int n0,
                   const float* __restrict__ s1, unsigned short* __restrict__ d1, int n1,
                   const float* __restrict__ s2, unsigned short* __restrict__ d2)
{
  int blk = blockIdx.x;
  const float* s; unsigned short* d;
  if (blk < n0)            { s = s0; d = d0; }
  else if (blk < n0 + n1)  { s = s1; d = d1; blk -= n0; }
  else                     { s = s2; d = d2; blk -= n0 + n1; }
  const size_t e = ((size_t)blk * 256 + threadIdx.x) * 8;
  const float4 a = *(const float4*)(s + e);
  const float4 b = *(const float4*)(s + e + 4);
  u16x8 v;
  v[0] = f2bf(a.x); v[1] = f2bf(a.y); v[2] = f2bf(a.z); v[3] = f2bf(a.w);
  v[4] = f2bf(b.x); v[5] = f2bf(b.y); v[6] = f2bf(b.z); v[7] = f2bf(b.w);
  *(u16x8*)(d + e) = v;
}

// ---------------------------------------------------------------------------
// 256x256 8-phase GEMM (T2+T3+T4+T5): out[m][n] = sum_k A[m][k]*B[n][k].
// 512 thr = 8 waves (2M x 4N), per-wave out 128x64. BK=64, 2 K-tiles/iter.
// LDS 128KB: As[2][256][64] + Bs[2][256][64] bf16, XOR-swizzled via
// inverse-swizzled global source + linear gload_lds dest (rule #21).
// Counted vmcnt(4) at phases 3/7 only; setprio around MFMA clusters.
// ---------------------------------------------------------------------------
#define STG(XS, Xg, buf, half, kt)                                              \
  { gload16((Xg) + (size_t)((half)*128 + srow8) * K + (kt)*64 + scol,           \
            (XS) + (buf)*32768 + (half)*16384 + wid*1024);                      \
    gload16((Xg) + (size_t)((half)*128 + 64 + srow8) * K + (kt)*64 + scol,      \
            (XS) + (buf)*32768 + (half)*16384 + 8192 + wid*1024); }

#define LDA(buf, ih)                                                            \
  { _Pragma("unroll") for (int i = 0; i < 4; ++i) {                             \
      const int ro = (buf)*32768 + arow + ((ih)*64 + i*16)*128;                 \
      af[i][0] = *(const bf16x8*)(As + ro + cbs0);                              \
      af[i][1] = *(const bf16x8*)(As + ro + cbs1); } }

#define LDB(buf, jh, BF)                                                        \
  { _Pragma("unroll") for (int j = 0; j < 2; ++j) {                             \
      const int ro = (buf)*32768 + brow + (((jh)*2 + j)*16)*128;                \
      BF[j][0] = *(const bf16x8*)(Bs + ro + cbs0);                              \
      BF[j][1] = *(const bf16x8*)(Bs + ro + cbs1); } }

#define MM(ih, jh, BF)                                                          \
  { _Pragma("unroll") for (int i = 0; i < 4; ++i)                               \
    _Pragma("unroll") for (int j = 0; j < 2; ++j)                               \
    _Pragma("unroll") for (int kk = 0; kk < 2; ++kk)                            \
      acc[(ih)*4+i][(jh)*2+j] = __builtin_amdgcn_mfma_f32_16x16x32_bf16(        \
          af[i][kk], BF[j][kk], acc[(ih)*4+i][(jh)*2+j], 0, 0, 0); }

#define BAR1_12() { asm volatile("s_waitcnt lgkmcnt(8)" ::: "memory");          \
                    __builtin_amdgcn_s_barrier();                               \
                    asm volatile("s_waitcnt lgkmcnt(0)" ::: "memory");          \
                    __builtin_amdgcn_sched_barrier(0);                          \
                    __builtin_amdgcn_s_setprio(1); }
#define BAR1()    { __builtin_amdgcn_s_barrier();                               \
                    asm volatile("s_waitcnt lgkmcnt(0)" ::: "memory");          \
                    __builtin_amdgcn_sched_barrier(0);                          \
                    __builtin_amdgcn_s_setprio(1); }
#define BAR2()    { __builtin_amdgcn_s_setprio(0); __builtin_amdgcn_s_barrier(); }
#define BAR2V()   { __builtin_amdgcn_s_setprio(0);                              \
                    asm volatile("s_waitcnt vmcnt(4)" ::: "memory");            \
                    __builtin_amdgcn_s_barrier(); }

template <bool OUTBF16>
__global__ __launch_bounds__(512, 2)
void gemm256_bt(const unsigned short* __restrict__ Ap, const unsigned short* __restrict__ Bp,
                void* __restrict__ Outp, int M, int N, int K)
{
  extern __shared__ __align__(16) char smem[];
  char* const As = smem;            // [2][256 rows][64 k] bf16, 64KB
  char* const Bs = smem + 65536;
  const int tid = threadIdx.x;
  const int wid = tid >> 6, lane = tid & 63;
  const int wm = wid >> 2, wn = wid & 3;
  const int lg = lane >> 4, lr = lane & 15;

  const int gx = gridDim.x;
  const int nwg = gx * (int)gridDim.y;
  int bid = (int)blockIdx.y * gx + (int)blockIdx.x;
  bid = (bid & 7) * (nwg >> 3) + (bid >> 3);   // bijective: nwg % 8 == 0
  const int m0 = (bid / gx) * 256, n0 = (bid % gx) * 256;

  const int srow8 = wid * 8 + (lane >> 3);
  const int scol  = (((lane & 7) ^ (lane >> 3)) << 3);
  const unsigned short* const Ag = Ap + (size_t)m0 * K;
  const unsigned short* const Bg = Bp + (size_t)n0 * K;

  const int cbs0 = (lg * 16) ^ ((lr & 7) << 4);        // kk=0 swizzled byte col
  const int cbs1 = (64 + lg * 16) ^ ((lr & 7) << 4);   // kk=1
  const int arow = (wm * 128 + lr) * 128;              // wave A base (bytes)
  const int brow = (wn * 64 + lr) * 128;               // wave B base (bytes)

  const f32x4 z4 = {0.f, 0.f, 0.f, 0.f};
  f32x4 acc[8][4];
#pragma unroll
  for (int i = 0; i < 8; ++i)
#pragma unroll
    for (int j = 0; j < 4; ++j) acc[i][j] = z4;

  const int NKT = K >> 6;
  bf16x8 af[4][2], bf01[2][2], bf23[2][2];

  // prologue: T0 = tile0 (A+B -> buf0), T1 = tile1 (B -> buf1)
  STG(As, Ag, 0, 0, 0); STG(As, Ag, 0, 1, 0);
  STG(Bs, Bg, 0, 0, 0); STG(Bs, Bg, 0, 1, 0);
  STG(Bs, Bg, 1, 0, 1); STG(Bs, Bg, 1, 1, 1);
  asm volatile("s_waitcnt vmcnt(4)" ::: "memory");
  __builtin_amdgcn_s_barrier();

  for (int it = 0; it < (NKT >> 1); ++it) {
    const int t1  = 2 * it + 1;
    const int t0n = (2 * it + 2 < NKT) ? 2 * it + 2 : NKT - 1;  // clamped tail
    const int t1n = (t1 + 2 < NKT) ? t1 + 2 : NKT - 1;

    // ph0: af(i0-3)+bf01 of T0(buf0) [12 reads]; stage A-h0(T1->buf1)
    LDA(0, 0); LDB(0, 0, bf01); STG(As, Ag, 1, 0, t1);
    BAR1_12(); MM(0, 0, bf01); BAR2();
    // ph1: bf23(T0) [4]; stage A-h1(T1->buf1)
    LDB(0, 1, bf23); STG(As, Ag, 1, 1, t1);
    BAR1(); MM(0, 1, bf23); BAR2();
    // ph2: af(i4-7)(T0) [8]; stage B-h0(T0+2->buf0)  [B buf0 free after ph1]
    LDA(0, 1); STG(Bs, Bg, 0, 0, t0n);
    BAR1(); MM(1, 0, bf01); BAR2();
    // ph3: stage B-h1(T0+2->buf0); vmcnt(4) gates T1 residency
    STG(Bs, Bg, 0, 1, t0n);
    BAR1(); MM(1, 1, bf23); BAR2V();
    // ph4: af(i0-3)+bf01 of T1(buf1) [12]; stage A-h0(T0+2->buf0)
    LDA(1, 0); LDB(1, 0, bf01); STG(As, Ag, 0, 0, t0n);
    BAR1_12(); MM(0, 0, bf01); BAR2();
    // ph5: bf23(T1) [4]; stage A-h1(T0+2->buf0)
    LDB(1, 1, bf23); STG(As, Ag, 0, 1, t0n);
    BAR1(); MM(0, 1, bf23); BAR2();
    // ph6: af(i4-7)(T1) [8]; stage B-h0(T1+2->buf1)
    LDA(1, 1); STG(Bs, Bg, 1, 0, t1n);
    BAR1(); MM(1, 0, bf01); BAR2();
    // ph7: stage B-h1(T1+2->buf1); vmcnt(4) gates T0+2 residency
    STG(Bs, Bg, 1, 1, t1n);
    BAR1(); MM(1, 1, bf23); BAR2V();
  }
  asm volatile("s_waitcnt vmcnt(0)" ::: "memory");  // drain before LDS dealloc

  // epilogue: C/D col=lane&15, row=(lane>>4)*4+reg
#pragma unroll
  for (int i = 0; i < 8; ++i)
#pragma unroll
    for (int j = 0; j < 4; ++j)
#pragma unroll
      for (int r = 0; r < 4; ++r) {
        const int row = m0 + wm * 128 + i * 16 + lg * 4 + r;
        const int col = n0 + wn * 64 + j * 16 + lr;
        const float val = acc[i][j][r];
        if (OUTBF16) ((unsigned short*)Outp)[(size_t)row * N + col] = f2bf(val);
        else         ((float*)Outp)[(size_t)row * N + col] = val;
      }
}

// ---------------------------------------------------------------------------
// GEMM (m97 structure) + XCD swizzle — kept for gemm3 (N=2048: 512 blocks).
// ---------------------------------------------------------------------------
template <bool OUTBF16>
__global__ __launch_bounds__(256, 2)
void gemm_bt16(const unsigned short* __restrict__ Ap, const unsigned short* __restrict__ Bp,
               void* __restrict__ Outp, int M, int N, int K)
{
  __shared__ __align__(16) char smA[128 * 128];
  __shared__ __align__(16) char smB[128 * 128];
  const int tid = threadIdx.x;
  const int wid = tid >> 6, lane = tid & 63;
  const int wr = wid >> 1, wc = wid & 1;
  const int lg = lane >> 4, lr = lane & 15;

  const int gx = gridDim.x;
  const int nwg = gx * gridDim.y;
  int bid = blockIdx.y * gx + blockIdx.x;
  bid = (bid & 7) * (nwg >> 3) + (bid >> 3);
  const int m0 = (bid / gx) * 128, n0 = (bid % gx) * 128;

  const int srow = wid * 8 + (lane >> 3);
  const int scol = (((lane & 7) ^ (lane >> 3)) << 3);
  const int lbase = wid * 1024;

  const f32x4 z4 = {0.f, 0.f, 0.f, 0.f};
  f32x4 acc[4][4];
#pragma unroll
  for (int i = 0; i < 4; ++i)
#pragma unroll
    for (int j = 0; j < 4; ++j) acc[i][j] = z4;

  for (int k0 = 0; k0 < K; k0 += 64) {
    __syncthreads();
#pragma unroll
    for (int c = 0; c < 4; ++c) {
      const int row = c * 32 + srow;
      gload16(Ap + (size_t)(m0 + row) * K + k0 + scol, smA + c * 4096 + lbase);
      gload16(Bp + (size_t)(n0 + row) * K + k0 + scol, smB + c * 4096 + lbase);
    }
    __syncthreads();
#pragma unroll
    for (int kk = 0; kk < 2; ++kk) {
      const int cb = (kk * 32 + lg * 8) * 2;
      bf16x8 a4[4], b4[4];
#pragma unroll
      for (int i = 0; i < 4; ++i) {
        const int row = wr * 64 + i * 16 + lr;
        a4[i] = *(const bf16x8*)(smA + row * 128 + (cb ^ ((row & 7) << 4)));
      }
#pragma unroll
      for (int j = 0; j < 4; ++j) {
        const int row = wc * 64 + j * 16 + lr;
        b4[j] = *(const bf16x8*)(smB + row * 128 + (cb ^ ((row & 7) << 4)));
      }
#pragma unroll
      for (int i = 0; i < 4; ++i)
#pragma unroll
        for (int j = 0; j < 4; ++j)
          acc[i][j] = __builtin_amdgcn_mfma_f32_16x16x32_bf16(a4[i], b4[j], acc[i][j], 0, 0, 0);
    }
  }
#pragma unroll
  for (int i = 0; i < 4; ++i)
#pragma unroll
    for (int j = 0; j < 4; ++j)
#pragma unroll
      for (int r = 0; r < 4; ++r) {
        const int row = m0 + wr * 64 + i * 16 + lg * 4 + r;
        const int col = n0 + wc * 64 + j * 16 + lr;
        const float val = acc[i][j][r];
        if (OUTBF16) ((unsigned short*)Outp)[(size_t)row * N + col] = f2bf(val);
        else         ((float*)Outp)[(size_t)row * N + col] = val;
      }
}

// ---------------------------------------------------------------------------
// V transpose: qkv V-part -> vT[(bh*128+d)*2048 + t]   (unchanged)
// ---------------------------------------------------------------------------
__global__ __launch_bounds__(256)
void vtrans(const unsigned short* __restrict__ qkv, unsigned short* __restrict__ vT)
{
  constexpr int T = 2048, ROWS = 6144;
  const int bh = blockIdx.y, b = bh >> 4, h = bh & 15;
  const int t0 = blockIdx.x * 64;
  const int tid = threadIdx.x;
  __shared__ __align__(16) char Sc[64 * 256];

#pragma unroll
  for (int c = 0; c < 4; ++c) {
    const int row = c * 16 + (tid >> 4);
    const int col = (tid & 15) * 8;
    u16x8 v = *(const u16x8*)(qkv + (size_t)(b * T + t0 + row) * ROWS + 4096 + h * 128 + col);
    *(u16x8*)(Sc + row * 256 + ((col * 2) ^ ((row & 7) << 4))) = v;
  }
  __syncthreads();
#pragma unroll
  for (int c = 0; c < 4; ++c) {
    const int d = c * 32 + (tid >> 3);
    const int t = (tid & 7) * 8;
    u16x8 v;
#pragma unroll
    for (int i = 0; i < 8; ++i)
      v[i] = *(const unsigned short*)(Sc + (t + i) * 256 + ((d * 2) ^ (((t + i) & 7) << 4)));
    *(u16x8*)(vT + ((size_t)bh * 128 + d) * 2048 + t0 + t) = v;
  }
}

// ---------------------------------------------------------------------------
// Flash attention v5 (unchanged from R5): gload_lds staged K and V^T, DPP
// softmax, 40KB LDS, 4 blocks/CU.
// ---------------------------------------------------------------------------
__global__ __launch_bounds__(256, 4)
void attn_fwd(const unsigned short* __restrict__ qkv, const unsigned short* __restrict__ vT,
              unsigned short* __restrict__ outp)
{
  constexpr int T = 2048, ROWS = 6144;
  const int qt = (int)gridDim.x - 1 - (int)blockIdx.x;
  const int bh = blockIdx.y;
  const int b = bh >> 4, h = bh & 15;
  const int q0 = qt * 64;
  const int tid = threadIdx.x;
  const int wid = tid >> 6, lane = tid & 63;
  const int lg = lane >> 4, lr = lane & 15;

  __shared__ __align__(16) char Ks[64 * 256];
  __shared__ __align__(16) char Vt[128 * 128];
  __shared__ __align__(16) char Ps[64 * 128];

  const int krow = wid * 4 + (lane >> 4);
  const int kcol = (((lane & 15) ^ (krow & 7)) << 3);
  const int vrow_s = wid * 8 + (lane >> 3);
  const int vcol_s = (((lane & 7) ^ (vrow_s & 7)) << 3);

  const size_t qrow = (size_t)(b * T + q0 + wid * 16 + lr) * ROWS + h * 128;
  bf16x8 qf[4];
#pragma unroll
  for (int kd = 0; kd < 4; ++kd)
    qf[kd] = __builtin_bit_cast(bf16x8, *(const u16x8*)(qkv + qrow + kd * 32 + lg * 8));

  const f32x4 z4 = {0.f, 0.f, 0.f, 0.f};
  f32x4 oacc[8];
#pragma unroll
  for (int jj = 0; jj < 8; ++jj) oacc[jj] = z4;
  float mrow[4] = {-1e30f, -1e30f, -1e30f, -1e30f};
  float lsum[4] = {0.f, 0.f, 0.f, 0.f};
  const float scale = 0.08838834764831845f;

  for (int kt = 0; kt <= qt; ++kt) {
    const int kbase = b * T + kt * 64;
    __syncthreads();
#pragma unroll
    for (int c = 0; c < 4; ++c) {
      gload16(qkv + (size_t)(kbase + c * 16 + krow) * ROWS + 2048 + h * 128 + kcol,
              Ks + c * 4096 + wid * 1024);
      gload16(vT + ((size_t)bh * 128 + c * 32 + vrow_s) * 2048 + kt * 64 + vcol_s,
              Vt + c * 4096 + wid * 1024);
    }
    asm volatile("s_waitcnt vmcnt(0)" ::: "memory");
    __syncthreads();

    f32x4 sf[4];
#pragma unroll
    for (int j = 0; j < 4; ++j) sf[j] = z4;
#pragma unroll
    for (int kd = 0; kd < 4; ++kd) {
      const int cb = (kd * 32 + lg * 8) * 2;
#pragma unroll
      for (int j = 0; j < 4; ++j) {
        const int row = j * 16 + lr;
        bf16x8 kf = *(const bf16x8*)(Ks + row * 256 + (cb ^ ((row & 7) << 4)));
        sf[j] = __builtin_amdgcn_mfma_f32_16x16x32_bf16(qf[kd], kf, sf[j], 0, 0, 0);
      }
    }

    const bool diag = (kt == qt);
#pragma unroll
    for (int j = 0; j < 4; ++j)
#pragma unroll
      for (int r = 0; r < 4; ++r) {
        float s = sf[j][r] * scale;
        if (diag && (j * 16 + lr > wid * 16 + lg * 4 + r)) s = -1e30f;
        sf[j][r] = s;
      }
    float alpha[4];
#pragma unroll
    for (int r = 0; r < 4; ++r) {
      const float pm = red16max(fmaxf(fmaxf(sf[0][r], sf[1][r]), fmaxf(sf[2][r], sf[3][r])));
      const float mn = fmaxf(mrow[r], pm);
      alpha[r] = __expf(mrow[r] - mn);
      mrow[r] = mn;
    }
    float rs[4] = {0.f, 0.f, 0.f, 0.f};
#pragma unroll
    for (int j = 0; j < 4; ++j)
#pragma unroll
      for (int r = 0; r < 4; ++r) {
        const float p = __expf(sf[j][r] - mrow[r]);
        sf[j][r] = p;
        rs[r] += p;
      }
#pragma unroll
    for (int r = 0; r < 4; ++r) lsum[r] = lsum[r] * alpha[r] + red16sum(rs[r]);

#pragma unroll
    for (int j = 0; j < 4; ++j)
#pragma unroll
      for (int r = 0; r < 4; ++r) {
        const int prow = wid * 16 + lg * 4 + r;
        const int pcol = j * 16 + lr;
        *(unsigned short*)(Ps + prow * 128 + ((pcol * 2) ^ ((prow & 7) << 4))) = f2bf(sf[j][r]);
      }
#pragma unroll
    for (int jj = 0; jj < 8; ++jj)
#pragma unroll
      for (int r = 0; r < 4; ++r) oacc[jj][r] *= alpha[r];
    asm volatile("s_waitcnt lgkmcnt(0)" ::: "memory");
    __builtin_amdgcn_sched_barrier(0);

#pragma unroll
    for (int kk = 0; kk < 2; ++kk) {
      const int prow = wid * 16 + lr;
      const int pcb = (kk * 32 + lg * 8) * 2;
      bf16x8 pf = *(const bf16x8*)(Ps + prow * 128 + (pcb ^ ((prow & 7) << 4)));
#pragma unroll
      for (int jj = 0; jj < 8; ++jj) {
        const int vrow = jj * 16 + lr;
        bf16x8 vf = *(const bf16x8*)(Vt + vrow * 128 + (pcb ^ ((vrow & 7) << 4)));
        oacc[jj] = __builtin_amdgcn_mfma_f32_16x16x32_bf16(pf, vf, oacc[jj], 0, 0, 0);
      }
    }
  }

#pragma unroll
  for (int jj = 0; jj < 8; ++jj)
#pragma unroll
    for (int r = 0; r < 4; ++r) {
      const int q = q0 + wid * 16 + lg * 4 + r;
      const int col = h * 128 + jj * 16 + lr;
      const float o = oacc[jj][r] / lsum[r];
      outp[(size_t)(b * T + q) * 2048 + col] = f2bf(o);
    }
}

// ---------------------------------------------------------------------------
extern "C" void kernel_launch(void* const* d_in, const int* in_sizes, int n_in,
                              void* d_out, int out_size, void* d_ws, size_t ws_size,
                              hipStream_t stream) {
  (void)in_sizes; (void)n_in; (void)out_size; (void)ws_size;
  const float* x     = (const float*)d_in[0];   // [2,2048,2048]
  const float* qkvw  = (const float*)d_in[1];   // [6144,2048]
  const float* projw = (const float*)d_in[2];   // [2048,2048]

  unsigned short* qkvb   = (unsigned short*)d_ws;               // [4096][6144]
  unsigned short* attnb  = qkvb   + (size_t)4096 * 6144;        // [4096][2048]
  unsigned short* xb     = attnb  + (size_t)4096 * 2048;        // [4096][2048]
  unsigned short* qkvwb  = xb     + (size_t)4096 * 2048;        // [6144][2048]
  unsigned short* projwb = qkvwb  + (size_t)6144 * 2048;        // [2048][2048]
  unsigned short* vT     = xb;                                  // overlay (xb dead after gemm1)
  float* out = (float*)d_out;                                   // [4096][2048] f32

  static bool attr_set = false;
  if (!attr_set) {
    hipFuncSetAttribute((const void*)gemm256_bt<true>,
                        hipFuncAttributeMaxDynamicSharedMemorySize, 131072);
    attr_set = true;
  }

  cvt3_f32_bf16<<<4096 + 6144 + 2048, 256, 0, stream>>>(
      x, xb, 4096, qkvw, qkvwb, 6144, projw, projwb);
  // qkv projection: 4096 x 6144 x 2048, 8-phase 256^2 (384 blocks)
  gemm256_bt<true><<<dim3(6144 / 256, 4096 / 256), 512, 131072, stream>>>(
      xb, qkvwb, qkvb, 4096, 6144, 2048);
  vtrans<<<dim3(32, 32), 256, 0, stream>>>(qkvb, vT);
  attn_fwd<<<dim3(32, 32), 256, 0, stream>>>(qkvb, vT, attnb);
  gemm_bt16<false><<<dim3(2048 / 128, 4096 / 128), 256, 0, stream>>>(
      attnb, projwb, out, 4096, 2048, 2048);
}

// Round 8
// 275.413 us; speedup vs baseline: 1.4865x; 1.0834x over previous
//
#include <hip/hip_runtime.h>

typedef __bf16 bf16x8 __attribute__((ext_vector_type(8)));
typedef float f32x4 __attribute__((ext_vector_type(4)));
typedef unsigned short u16x8 __attribute__((ext_vector_type(8)));

__device__ __forceinline__ unsigned short f2bf(float f) {
  return __builtin_bit_cast(unsigned short, (__bf16)f);   // v_cvt_pk_bf16_f32, RNE
}

__device__ __forceinline__ void gload16(const void* g, void* l) {
  __builtin_amdgcn_global_load_lds((const __attribute__((address_space(1))) unsigned int*)g,
                                   (__attribute__((address_space(3))) unsigned int*)l,
                                   16, 0, 0);
}

// DPP row_ror reductions over 16-lane rows (VALU pipe, no LDS traffic)
template <int N>
__device__ __forceinline__ float rormax(float x) {
  int r = __builtin_amdgcn_update_dpp(0, __builtin_bit_cast(int, x), 0x120 + N, 0xF, 0xF, true);
  return fmaxf(x, __builtin_bit_cast(float, r));
}
template <int N>
__device__ __forceinline__ float rorsum(float x) {
  int r = __builtin_amdgcn_update_dpp(0, __builtin_bit_cast(int, x), 0x120 + N, 0xF, 0xF, true);
  return x + __builtin_bit_cast(float, r);
}
__device__ __forceinline__ float red16max(float x) {
  x = rormax<8>(x); x = rormax<4>(x); x = rormax<2>(x); return rormax<1>(x);
}
__device__ __forceinline__ float red16sum(float x) {
  x = rorsum<8>(x); x = rorsum<4>(x); x = rorsum<2>(x); return rorsum<1>(x);
}

// ---------------------------------------------------------------------------
// f32 -> bf16 conversion for {x, qkv_w, proj_w}
// ---------------------------------------------------------------------------
__global__ __launch_bounds__(256)
void cvt3_f32_bf16(const float* __restrict__ s0, unsigned short* __restrict__ d0, int n0,
                   const float* __restrict__ s1, unsigned short* __restrict__ d1, int n1,
                   const float* __restrict__ s2, unsigned short* __restrict__ d2)
{
  int blk = blockIdx.x;
  const float* s; unsigned short* d;
  if (blk < n0)            { s = s0; d = d0; }
  else if (blk < n0 + n1)  { s = s1; d = d1; blk -= n0; }
  else                     { s = s2; d = d2; blk -= n0 + n1; }
  const size_t e = ((size_t)blk * 256 + threadIdx.x) * 8;
  const float4 a = *(const float4*)(s + e);
  const float4 b = *(const float4*)(s + e + 4);
  u16x8 v;
  v[0] = f2bf(a.x); v[1] = f2bf(a.y); v[2] = f2bf(a.z); v[3] = f2bf(a.w);
  v[4] = f2bf(b.x); v[5] = f2bf(b.y); v[6] = f2bf(b.z); v[7] = f2bf(b.w);
  *(u16x8*)(d + e) = v;
}

// ---------------------------------------------------------------------------
// 256x256 8-phase GEMM (T2+T3+T4+T5). Unchanged from R6.
// ---------------------------------------------------------------------------
#define STG(XS, Xg, buf, half, kt)                                              \
  { gload16((Xg) + (size_t)((half)*128 + srow8) * K + (kt)*64 + scol,           \
            (XS) + (buf)*32768 + (half)*16384 + wid*1024);                      \
    gload16((Xg) + (size_t)((half)*128 + 64 + srow8) * K + (kt)*64 + scol,      \
            (XS) + (buf)*32768 + (half)*16384 + 8192 + wid*1024); }

#define LDA(buf, ih)                                                            \
  { _Pragma("unroll") for (int i = 0; i < 4; ++i) {                             \
      const int ro = (buf)*32768 + arow + ((ih)*64 + i*16)*128;                 \
      af[i][0] = *(const bf16x8*)(As + ro + cbs0);                              \
      af[i][1] = *(const bf16x8*)(As + ro + cbs1); } }

#define LDB(buf, jh, BF)                                                        \
  { _Pragma("unroll") for (int j = 0; j < 2; ++j) {                             \
      const int ro = (buf)*32768 + brow + (((jh)*2 + j)*16)*128;                \
      BF[j][0] = *(const bf16x8*)(Bs + ro + cbs0);                              \
      BF[j][1] = *(const bf16x8*)(Bs + ro + cbs1); } }

#define MM(ih, jh, BF)                                                          \
  { _Pragma("unroll") for (int i = 0; i < 4; ++i)                               \
    _Pragma("unroll") for (int j = 0; j < 2; ++j)                               \
    _Pragma("unroll") for (int kk = 0; kk < 2; ++kk)                            \
      acc[(ih)*4+i][(jh)*2+j] = __builtin_amdgcn_mfma_f32_16x16x32_bf16(        \
          af[i][kk], BF[j][kk], acc[(ih)*4+i][(jh)*2+j], 0, 0, 0); }

#define BAR1_12() { asm volatile("s_waitcnt lgkmcnt(8)" ::: "memory");          \
                    __builtin_amdgcn_s_barrier();                               \
                    asm volatile("s_waitcnt lgkmcnt(0)" ::: "memory");          \
                    __builtin_amdgcn_sched_barrier(0);                          \
                    __builtin_amdgcn_s_setprio(1); }
#define BAR1()    { __builtin_amdgcn_s_barrier();                               \
                    asm volatile("s_waitcnt lgkmcnt(0)" ::: "memory");          \
                    __builtin_amdgcn_sched_barrier(0);                          \
                    __builtin_amdgcn_s_setprio(1); }
#define BAR2()    { __builtin_amdgcn_s_setprio(0); __builtin_amdgcn_s_barrier(); }
#define BAR2V()   { __builtin_amdgcn_s_setprio(0);                              \
                    asm volatile("s_waitcnt vmcnt(4)" ::: "memory");            \
                    __builtin_amdgcn_s_barrier(); }

template <bool OUTBF16>
__global__ __launch_bounds__(512, 2)
void gemm256_bt(const unsigned short* __restrict__ Ap, const unsigned short* __restrict__ Bp,
                void* __restrict__ Outp, int M, int N, int K)
{
  extern __shared__ __align__(16) char smem[];
  char* const As = smem;            // [2][256 rows][64 k] bf16, 64KB
  char* const Bs = smem + 65536;
  const int tid = threadIdx.x;
  const int wid = tid >> 6, lane = tid & 63;
  const int wm = wid >> 2, wn = wid & 3;
  const int lg = lane >> 4, lr = lane & 15;

  const int gx = gridDim.x;
  const int nwg = gx * (int)gridDim.y;
  int bid = (int)blockIdx.y * gx + (int)blockIdx.x;
  bid = (bid & 7) * (nwg >> 3) + (bid >> 3);   // bijective: nwg % 8 == 0
  const int m0 = (bid / gx) * 256, n0 = (bid % gx) * 256;

  const int srow8 = wid * 8 + (lane >> 3);
  const int scol  = (((lane & 7) ^ (lane >> 3)) << 3);
  const unsigned short* const Ag = Ap + (size_t)m0 * K;
  const unsigned short* const Bg = Bp + (size_t)n0 * K;

  const int cbs0 = (lg * 16) ^ ((lr & 7) << 4);
  const int cbs1 = (64 + lg * 16) ^ ((lr & 7) << 4);
  const int arow = (wm * 128 + lr) * 128;
  const int brow = (wn * 64 + lr) * 128;

  const f32x4 z4 = {0.f, 0.f, 0.f, 0.f};
  f32x4 acc[8][4];
#pragma unroll
  for (int i = 0; i < 8; ++i)
#pragma unroll
    for (int j = 0; j < 4; ++j) acc[i][j] = z4;

  const int NKT = K >> 6;
  bf16x8 af[4][2], bf01[2][2], bf23[2][2];

  STG(As, Ag, 0, 0, 0); STG(As, Ag, 0, 1, 0);
  STG(Bs, Bg, 0, 0, 0); STG(Bs, Bg, 0, 1, 0);
  STG(Bs, Bg, 1, 0, 1); STG(Bs, Bg, 1, 1, 1);
  asm volatile("s_waitcnt vmcnt(4)" ::: "memory");
  __builtin_amdgcn_s_barrier();

  for (int it = 0; it < (NKT >> 1); ++it) {
    const int t1  = 2 * it + 1;
    const int t0n = (2 * it + 2 < NKT) ? 2 * it + 2 : NKT - 1;
    const int t1n = (t1 + 2 < NKT) ? t1 + 2 : NKT - 1;

    LDA(0, 0); LDB(0, 0, bf01); STG(As, Ag, 1, 0, t1);
    BAR1_12(); MM(0, 0, bf01); BAR2();
    LDB(0, 1, bf23); STG(As, Ag, 1, 1, t1);
    BAR1(); MM(0, 1, bf23); BAR2();
    LDA(0, 1); STG(Bs, Bg, 0, 0, t0n);
    BAR1(); MM(1, 0, bf01); BAR2();
    STG(Bs, Bg, 0, 1, t0n);
    BAR1(); MM(1, 1, bf23); BAR2V();
    LDA(1, 0); LDB(1, 0, bf01); STG(As, Ag, 0, 0, t0n);
    BAR1_12(); MM(0, 0, bf01); BAR2();
    LDB(1, 1, bf23); STG(As, Ag, 0, 1, t0n);
    BAR1(); MM(0, 1, bf23); BAR2();
    LDA(1, 1); STG(Bs, Bg, 1, 0, t1n);
    BAR1(); MM(1, 0, bf01); BAR2();
    STG(Bs, Bg, 1, 1, t1n);
    BAR1(); MM(1, 1, bf23); BAR2V();
  }
  asm volatile("s_waitcnt vmcnt(0)" ::: "memory");

#pragma unroll
  for (int i = 0; i < 8; ++i)
#pragma unroll
    for (int j = 0; j < 4; ++j)
#pragma unroll
      for (int r = 0; r < 4; ++r) {
        const int row = m0 + wm * 128 + i * 16 + lg * 4 + r;
        const int col = n0 + wn * 64 + j * 16 + lr;
        const float val = acc[i][j][r];
        if (OUTBF16) ((unsigned short*)Outp)[(size_t)row * N + col] = f2bf(val);
        else         ((float*)Outp)[(size_t)row * N + col] = val;
      }
}

// ---------------------------------------------------------------------------
// GEMM (m97 structure) + XCD swizzle — gemm3 (N=2048: 512 blocks).
// ---------------------------------------------------------------------------
template <bool OUTBF16>
__global__ __launch_bounds__(256, 2)
void gemm_bt16(const unsigned short* __restrict__ Ap, const unsigned short* __restrict__ Bp,
               void* __restrict__ Outp, int M, int N, int K)
{
  __shared__ __align__(16) char smA[128 * 128];
  __shared__ __align__(16) char smB[128 * 128];
  const int tid = threadIdx.x;
  const int wid = tid >> 6, lane = tid & 63;
  const int wr = wid >> 1, wc = wid & 1;
  const int lg = lane >> 4, lr = lane & 15;

  const int gx = gridDim.x;
  const int nwg = gx * gridDim.y;
  int bid = blockIdx.y * gx + blockIdx.x;
  bid = (bid & 7) * (nwg >> 3) + (bid >> 3);
  const int m0 = (bid / gx) * 128, n0 = (bid % gx) * 128;

  const int srow = wid * 8 + (lane >> 3);
  const int scol = (((lane & 7) ^ (lane >> 3)) << 3);
  const int lbase = wid * 1024;

  const f32x4 z4 = {0.f, 0.f, 0.f, 0.f};
  f32x4 acc[4][4];
#pragma unroll
  for (int i = 0; i < 4; ++i)
#pragma unroll
    for (int j = 0; j < 4; ++j) acc[i][j] = z4;

  for (int k0 = 0; k0 < K; k0 += 64) {
    __syncthreads();
#pragma unroll
    for (int c = 0; c < 4; ++c) {
      const int row = c * 32 + srow;
      gload16(Ap + (size_t)(m0 + row) * K + k0 + scol, smA + c * 4096 + lbase);
      gload16(Bp + (size_t)(n0 + row) * K + k0 + scol, smB + c * 4096 + lbase);
    }
    __syncthreads();
#pragma unroll
    for (int kk = 0; kk < 2; ++kk) {
      const int cb = (kk * 32 + lg * 8) * 2;
      bf16x8 a4[4], b4[4];
#pragma unroll
      for (int i = 0; i < 4; ++i) {
        const int row = wr * 64 + i * 16 + lr;
        a4[i] = *(const bf16x8*)(smA + row * 128 + (cb ^ ((row & 7) << 4)));
      }
#pragma unroll
      for (int j = 0; j < 4; ++j) {
        const int row = wc * 64 + j * 16 + lr;
        b4[j] = *(const bf16x8*)(smB + row * 128 + (cb ^ ((row & 7) << 4)));
      }
#pragma unroll
      for (int i = 0; i < 4; ++i)
#pragma unroll
        for (int j = 0; j < 4; ++j)
          acc[i][j] = __builtin_amdgcn_mfma_f32_16x16x32_bf16(a4[i], b4[j], acc[i][j], 0, 0, 0);
    }
  }
#pragma unroll
  for (int i = 0; i < 4; ++i)
#pragma unroll
    for (int j = 0; j < 4; ++j)
#pragma unroll
      for (int r = 0; r < 4; ++r) {
        const int row = m0 + wr * 64 + i * 16 + lg * 4 + r;
        const int col = n0 + wc * 64 + j * 16 + lr;
        const float val = acc[i][j][r];
        if (OUTBF16) ((unsigned short*)Outp)[(size_t)row * N + col] = f2bf(val);
        else         ((float*)Outp)[(size_t)row * N + col] = val;
      }
}

// ---------------------------------------------------------------------------
// V transpose: qkv V-part -> vT[(bh*128+d)*2048 + t]   (unchanged)
// ---------------------------------------------------------------------------
__global__ __launch_bounds__(256)
void vtrans(const unsigned short* __restrict__ qkv, unsigned short* __restrict__ vT)
{
  constexpr int T = 2048, ROWS = 6144;
  const int bh = blockIdx.y, b = bh >> 4, h = bh & 15;
  const int t0 = blockIdx.x * 64;
  const int tid = threadIdx.x;
  __shared__ __align__(16) char Sc[64 * 256];

#pragma unroll
  for (int c = 0; c < 4; ++c) {
    const int row = c * 16 + (tid >> 4);
    const int col = (tid & 15) * 8;
    u16x8 v = *(const u16x8*)(qkv + (size_t)(b * T + t0 + row) * ROWS + 4096 + h * 128 + col);
    *(u16x8*)(Sc + row * 256 + ((col * 2) ^ ((row & 7) << 4))) = v;
  }
  __syncthreads();
#pragma unroll
  for (int c = 0; c < 4; ++c) {
    const int d = c * 32 + (tid >> 3);
    const int t = (tid & 7) * 8;
    u16x8 v;
#pragma unroll
    for (int i = 0; i < 8; ++i)
      v[i] = *(const unsigned short*)(Sc + (t + i) * 256 + ((d * 2) ^ (((t + i) & 7) << 4)));
    *(u16x8*)(vT + ((size_t)bh * 128 + d) * 2048 + t0 + t) = v;
  }
}

// ---------------------------------------------------------------------------
// Flash attention v6: qt-major 1D grid (fixes qt->CU aliasing: CU gets
// qt in {q,q+8,q+16,q+24}, same bh -> balanced work + L2 reuse);
// log2-domain softmax (exp2f); T13 defer-max. LDS 40KB, 4 blocks/CU.
// ---------------------------------------------------------------------------
__global__ __launch_bounds__(256, 4)
void attn_fwd(const unsigned short* __restrict__ qkv, const unsigned short* __restrict__ vT,
              unsigned short* __restrict__ outp)
{
  constexpr int T = 2048, ROWS = 6144;
  const int blk = blockIdx.x;
  const int qt = blk >> 5;              // qt-major
  const int bh = blk & 31;
  const int b = bh >> 4, h = bh & 15;
  const int q0 = qt * 64;
  const int tid = threadIdx.x;
  const int wid = tid >> 6, lane = tid & 63;
  const int lg = lane >> 4, lr = lane & 15;

  __shared__ __align__(16) char Ks[64 * 256];
  __shared__ __align__(16) char Vt[128 * 128];
  __shared__ __align__(16) char Ps[64 * 128];

  const int krow = wid * 4 + (lane >> 4);
  const int kcol = (((lane & 15) ^ (krow & 7)) << 3);
  const int vrow_s = wid * 8 + (lane >> 3);
  const int vcol_s = (((lane & 7) ^ (vrow_s & 7)) << 3);

  const size_t qrow = (size_t)(b * T + q0 + wid * 16 + lr) * ROWS + h * 128;
  bf16x8 qf[4];
#pragma unroll
  for (int kd = 0; kd < 4; ++kd)
    qf[kd] = __builtin_bit_cast(bf16x8, *(const u16x8*)(qkv + qrow + kd * 32 + lg * 8));

  const f32x4 z4 = {0.f, 0.f, 0.f, 0.f};
  f32x4 oacc[8];
#pragma unroll
  for (int jj = 0; jj < 8; ++jj) oacc[jj] = z4;
  float mrow[4] = {-1e30f, -1e30f, -1e30f, -1e30f};
  float lsum[4] = {0.f, 0.f, 0.f, 0.f};
  const float scale2 = 0.12751745f;   // (1/sqrt(128)) * log2(e)

  for (int kt = 0; kt <= qt; ++kt) {
    const int kbase = b * T + kt * 64;
    __syncthreads();
#pragma unroll
    for (int c = 0; c < 4; ++c) {
      gload16(qkv + (size_t)(kbase + c * 16 + krow) * ROWS + 2048 + h * 128 + kcol,
              Ks + c * 4096 + wid * 1024);
      gload16(vT + ((size_t)bh * 128 + c * 32 + vrow_s) * 2048 + kt * 64 + vcol_s,
              Vt + c * 4096 + wid * 1024);
    }
    asm volatile("s_waitcnt vmcnt(0)" ::: "memory");
    __syncthreads();

    // S = Q K^T
    f32x4 sf[4];
#pragma unroll
    for (int j = 0; j < 4; ++j) sf[j] = z4;
#pragma unroll
    for (int kd = 0; kd < 4; ++kd) {
      const int cb = (kd * 32 + lg * 8) * 2;
#pragma unroll
      for (int j = 0; j < 4; ++j) {
        const int row = j * 16 + lr;
        bf16x8 kf = *(const bf16x8*)(Ks + row * 256 + (cb ^ ((row & 7) << 4)));
        sf[j] = __builtin_amdgcn_mfma_f32_16x16x32_bf16(qf[kd], kf, sf[j], 0, 0, 0);
      }
    }

    // softmax in log2 domain
    const bool diag = (kt == qt);
#pragma unroll
    for (int j = 0; j < 4; ++j)
#pragma unroll
      for (int r = 0; r < 4; ++r) {
        float s = sf[j][r] * scale2;
        if (diag && (j * 16 + lr > wid * 16 + lg * 4 + r)) s = -1e30f;
        sf[j][r] = s;
      }
    float pm[4];
#pragma unroll
    for (int r = 0; r < 4; ++r)
      pm[r] = red16max(fmaxf(fmaxf(sf[0][r], sf[1][r]), fmaxf(sf[2][r], sf[3][r])));
    // T13 defer-max: skip rescale when max growth <= 11.5 (log2 units)
    const float growth = fmaxf(fmaxf(pm[0] - mrow[0], pm[1] - mrow[1]),
                               fmaxf(pm[2] - mrow[2], pm[3] - mrow[3]));
    const bool resc = !__all(growth <= 11.5f);
    float alpha[4];
    if (resc) {
#pragma unroll
      for (int r = 0; r < 4; ++r) {
        const float mn = fmaxf(mrow[r], pm[r]);
        alpha[r] = exp2f(mrow[r] - mn);
        mrow[r] = mn;
      }
    }
    float rs[4] = {0.f, 0.f, 0.f, 0.f};
#pragma unroll
    for (int j = 0; j < 4; ++j)
#pragma unroll
      for (int r = 0; r < 4; ++r) {
        const float p = exp2f(sf[j][r] - mrow[r]);
        sf[j][r] = p;
        rs[r] += p;
      }
    if (resc) {
#pragma unroll
      for (int r = 0; r < 4; ++r) lsum[r] = lsum[r] * alpha[r] + red16sum(rs[r]);
    } else {
#pragma unroll
      for (int r = 0; r < 4; ++r) lsum[r] += red16sum(rs[r]);
    }

    // P -> Ps (wave-private rows)
#pragma unroll
    for (int j = 0; j < 4; ++j)
#pragma unroll
      for (int r = 0; r < 4; ++r) {
        const int prow = wid * 16 + lg * 4 + r;
        const int pcol = j * 16 + lr;
        *(unsigned short*)(Ps + prow * 128 + ((pcol * 2) ^ ((prow & 7) << 4))) = f2bf(sf[j][r]);
      }
    if (resc) {
#pragma unroll
      for (int jj = 0; jj < 8; ++jj)
#pragma unroll
        for (int r = 0; r < 4; ++r) oacc[jj][r] *= alpha[r];
    }
    asm volatile("s_waitcnt lgkmcnt(0)" ::: "memory");
    __builtin_amdgcn_sched_barrier(0);

    // O += P V
#pragma unroll
    for (int kk = 0; kk < 2; ++kk) {
      const int prow = wid * 16 + lr;
      const int pcb = (kk * 32 + lg * 8) * 2;
      bf16x8 pf = *(const bf16x8*)(Ps + prow * 128 + (pcb ^ ((prow & 7) << 4)));
#pragma unroll
      for (int jj = 0; jj < 8; ++jj) {
        const int vrow = jj * 16 + lr;
        bf16x8 vf = *(const bf16x8*)(Vt + vrow * 128 + (pcb ^ ((vrow & 7) << 4)));
        oacc[jj] = __builtin_amdgcn_mfma_f32_16x16x32_bf16(pf, vf, oacc[jj], 0, 0, 0);
      }
    }
  }

  // epilogue
#pragma unroll
  for (int jj = 0; jj < 8; ++jj)
#pragma unroll
    for (int r = 0; r < 4; ++r) {
      const int q = q0 + wid * 16 + lg * 4 + r;
      const int col = h * 128 + jj * 16 + lr;
      const float o = oacc[jj][r] / lsum[r];
      outp[(size_t)(b * T + q) * 2048 + col] = f2bf(o);
    }
}

// ---------------------------------------------------------------------------
extern "C" void kernel_launch(void* const* d_in, const int* in_sizes, int n_in,
                              void* d_out, int out_size, void* d_ws, size_t ws_size,
                              hipStream_t stream) {
  (void)in_sizes; (void)n_in; (void)out_size; (void)ws_size;
  const float* x     = (const float*)d_in[0];   // [2,2048,2048]
  const float* qkvw  = (const float*)d_in[1];   // [6144,2048]
  const float* projw = (const float*)d_in[2];   // [2048,2048]

  unsigned short* qkvb   = (unsigned short*)d_ws;               // [4096][6144]
  unsigned short* attnb  = qkvb   + (size_t)4096 * 6144;        // [4096][2048]
  unsigned short* xb     = attnb  + (size_t)4096 * 2048;        // [4096][2048]
  unsigned short* qkvwb  = xb     + (size_t)4096 * 2048;        // [6144][2048]
  unsigned short* projwb = qkvwb  + (size_t)6144 * 2048;        // [2048][2048]
  unsigned short* vT     = xb;                                  // overlay (xb dead after gemm1)
  float* out = (float*)d_out;                                   // [4096][2048] f32

  static bool attr_set = false;
  if (!attr_set) {
    hipFuncSetAttribute((const void*)gemm256_bt<true>,
                        hipFuncAttributeMaxDynamicSharedMemorySize, 131072);
    attr_set = true;
  }

  cvt3_f32_bf16<<<4096 + 6144 + 2048, 256, 0, stream>>>(
      x, xb, 4096, qkvw, qkvwb, 6144, projw, projwb);
  gemm256_bt<true><<<dim3(6144 / 256, 4096 / 256), 512, 131072, stream>>>(
      xb, qkvwb, qkvb, 4096, 6144, 2048);
  vtrans<<<dim3(32, 32), 256, 0, stream>>>(qkvb, vT);
  attn_fwd<<<1024, 256, 0, stream>>>(qkvb, vT, attnb);
  gemm_bt16<false><<<dim3(2048 / 128, 4096 / 128), 256, 0, stream>>>(
      attnb, projwb, out, 4096, 2048, 2048);
}

// Round 9
// 256.027 us; speedup vs baseline: 1.5990x; 1.0757x over previous
//
#include <hip/hip_runtime.h>

typedef __bf16 bf16x8 __attribute__((ext_vector_type(8)));
typedef float f32x4 __attribute__((ext_vector_type(4)));
typedef unsigned short u16x8 __attribute__((ext_vector_type(8)));

__device__ __forceinline__ unsigned short f2bf(float f) {
  return __builtin_bit_cast(unsigned short, (__bf16)f);   // v_cvt_pk_bf16_f32, RNE
}

__device__ __forceinline__ void gload16(const void* g, void* l) {
  __builtin_amdgcn_global_load_lds((const __attribute__((address_space(1))) unsigned int*)g,
                                   (__attribute__((address_space(3))) unsigned int*)l,
                                   16, 0, 0);
}

// DPP row_ror reductions over 16-lane rows (VALU pipe, no LDS traffic)
template <int N>
__device__ __forceinline__ float rormax(float x) {
  int r = __builtin_amdgcn_update_dpp(0, __builtin_bit_cast(int, x), 0x120 + N, 0xF, 0xF, true);
  return fmaxf(x, __builtin_bit_cast(float, r));
}
template <int N>
__device__ __forceinline__ float rorsum(float x) {
  int r = __builtin_amdgcn_update_dpp(0, __builtin_bit_cast(int, x), 0x120 + N, 0xF, 0xF, true);
  return x + __builtin_bit_cast(float, r);
}
__device__ __forceinline__ float red16max(float x) {
  x = rormax<8>(x); x = rormax<4>(x); x = rormax<2>(x); return rormax<1>(x);
}
__device__ __forceinline__ float red16sum(float x) {
  x = rorsum<8>(x); x = rorsum<4>(x); x = rorsum<2>(x); return rorsum<1>(x);
}

// ---------------------------------------------------------------------------
// f32 -> bf16 conversion for {x, qkv_w, proj_w}
// ---------------------------------------------------------------------------
__global__ __launch_bounds__(256)
void cvt3_f32_bf16(const float* __restrict__ s0, unsigned short* __restrict__ d0, int n0,
                   const float* __restrict__ s1, unsigned short* __restrict__ d1, int n1,
                   const float* __restrict__ s2, unsigned short* __restrict__ d2)
{
  int blk = blockIdx.x;
  const float* s; unsigned short* d;
  if (blk < n0)            { s = s0; d = d0; }
  else if (blk < n0 + n1)  { s = s1; d = d1; blk -= n0; }
  else                     { s = s2; d = d2; blk -= n0 + n1; }
  const size_t e = ((size_t)blk * 256 + threadIdx.x) * 8;
  const float4 a = *(const float4*)(s + e);
  const float4 b = *(const float4*)(s + e + 4);
  u16x8 v;
  v[0] = f2bf(a.x); v[1] = f2bf(a.y); v[2] = f2bf(a.z); v[3] = f2bf(a.w);
  v[4] = f2bf(b.x); v[5] = f2bf(b.y); v[6] = f2bf(b.z); v[7] = f2bf(b.w);
  *(u16x8*)(d + e) = v;
}

// ---------------------------------------------------------------------------
// 256x256 8-phase GEMM (T2+T3+T4+T5). Launch bounds relaxed to (512,1):
// LDS (128KB) already caps occupancy at 1 block/CU, so don't cap VGPRs.
// ---------------------------------------------------------------------------
#define STG(XS, Xg, buf, half, kt)                                              \
  { gload16((Xg) + (size_t)((half)*128 + srow8) * K + (kt)*64 + scol,           \
            (XS) + (buf)*32768 + (half)*16384 + wid*1024);                      \
    gload16((Xg) + (size_t)((half)*128 + 64 + srow8) * K + (kt)*64 + scol,      \
            (XS) + (buf)*32768 + (half)*16384 + 8192 + wid*1024); }

#define LDA(buf, ih)                                                            \
  { _Pragma("unroll") for (int i = 0; i < 4; ++i) {                             \
      const int ro = (buf)*32768 + arow + ((ih)*64 + i*16)*128;                 \
      af[i][0] = *(const bf16x8*)(As + ro + cbs0);                              \
      af[i][1] = *(const bf16x8*)(As + ro + cbs1); } }

#define LDB(buf, jh, BF)                                                        \
  { _Pragma("unroll") for (int j = 0; j < 2; ++j) {                             \
      const int ro = (buf)*32768 + brow + (((jh)*2 + j)*16)*128;                \
      BF[j][0] = *(const bf16x8*)(Bs + ro + cbs0);                              \
      BF[j][1] = *(const bf16x8*)(Bs + ro + cbs1); } }

#define MM(ih, jh, BF)                                                          \
  { _Pragma("unroll") for (int i = 0; i < 4; ++i)                               \
    _Pragma("unroll") for (int j = 0; j < 2; ++j)                               \
    _Pragma("unroll") for (int kk = 0; kk < 2; ++kk)                            \
      acc[(ih)*4+i][(jh)*2+j] = __builtin_amdgcn_mfma_f32_16x16x32_bf16(        \
          af[i][kk], BF[j][kk], acc[(ih)*4+i][(jh)*2+j], 0, 0, 0); }

#define BAR1_12() { asm volatile("s_waitcnt lgkmcnt(8)" ::: "memory");          \
                    __builtin_amdgcn_s_barrier();                               \
                    asm volatile("s_waitcnt lgkmcnt(0)" ::: "memory");          \
                    __builtin_amdgcn_sched_barrier(0);                          \
                    __builtin_amdgcn_s_setprio(1); }
#define BAR1()    { __builtin_amdgcn_s_barrier();                               \
                    asm volatile("s_waitcnt lgkmcnt(0)" ::: "memory");          \
                    __builtin_amdgcn_sched_barrier(0);                          \
                    __builtin_amdgcn_s_setprio(1); }
#define BAR2()    { __builtin_amdgcn_s_setprio(0); __builtin_amdgcn_s_barrier(); }
#define BAR2V()   { __builtin_amdgcn_s_setprio(0);                              \
                    asm volatile("s_waitcnt vmcnt(4)" ::: "memory");            \
                    __builtin_amdgcn_s_barrier(); }

template <bool OUTBF16>
__global__ __launch_bounds__(512, 1)
void gemm256_bt(const unsigned short* __restrict__ Ap, const unsigned short* __restrict__ Bp,
                void* __restrict__ Outp, int M, int N, int K)
{
  extern __shared__ __align__(16) char smem[];
  char* const As = smem;            // [2][256 rows][64 k] bf16, 64KB
  char* const Bs = smem + 65536;
  const int tid = threadIdx.x;
  const int wid = tid >> 6, lane = tid & 63;
  const int wm = wid >> 2, wn = wid & 3;
  const int lg = lane >> 4, lr = lane & 15;

  const int gx = gridDim.x;
  const int nwg = gx * (int)gridDim.y;
  int bid = (int)blockIdx.y * gx + (int)blockIdx.x;
  bid = (bid & 7) * (nwg >> 3) + (bid >> 3);   // bijective: nwg % 8 == 0
  const int m0 = (bid / gx) * 256, n0 = (bid % gx) * 256;

  const int srow8 = wid * 8 + (lane >> 3);
  const int scol  = (((lane & 7) ^ (lane >> 3)) << 3);
  const unsigned short* const Ag = Ap + (size_t)m0 * K;
  const unsigned short* const Bg = Bp + (size_t)n0 * K;

  const int cbs0 = (lg * 16) ^ ((lr & 7) << 4);
  const int cbs1 = (64 + lg * 16) ^ ((lr & 7) << 4);
  const int arow = (wm * 128 + lr) * 128;
  const int brow = (wn * 64 + lr) * 128;

  const f32x4 z4 = {0.f, 0.f, 0.f, 0.f};
  f32x4 acc[8][4];
#pragma unroll
  for (int i = 0; i < 8; ++i)
#pragma unroll
    for (int j = 0; j < 4; ++j) acc[i][j] = z4;

  const int NKT = K >> 6;
  bf16x8 af[4][2], bf01[2][2], bf23[2][2];

  STG(As, Ag, 0, 0, 0); STG(As, Ag, 0, 1, 0);
  STG(Bs, Bg, 0, 0, 0); STG(Bs, Bg, 0, 1, 0);
  STG(Bs, Bg, 1, 0, 1); STG(Bs, Bg, 1, 1, 1);
  asm volatile("s_waitcnt vmcnt(4)" ::: "memory");
  __builtin_amdgcn_s_barrier();

  for (int it = 0; it < (NKT >> 1); ++it) {
    const int t1  = 2 * it + 1;
    const int t0n = (2 * it + 2 < NKT) ? 2 * it + 2 : NKT - 1;
    const int t1n = (t1 + 2 < NKT) ? t1 + 2 : NKT - 1;

    LDA(0, 0); LDB(0, 0, bf01); STG(As, Ag, 1, 0, t1);
    BAR1_12(); MM(0, 0, bf01); BAR2();
    LDB(0, 1, bf23); STG(As, Ag, 1, 1, t1);
    BAR1(); MM(0, 1, bf23); BAR2();
    LDA(0, 1); STG(Bs, Bg, 0, 0, t0n);
    BAR1(); MM(1, 0, bf01); BAR2();
    STG(Bs, Bg, 0, 1, t0n);
    BAR1(); MM(1, 1, bf23); BAR2V();
    LDA(1, 0); LDB(1, 0, bf01); STG(As, Ag, 0, 0, t0n);
    BAR1_12(); MM(0, 0, bf01); BAR2();
    LDB(1, 1, bf23); STG(As, Ag, 0, 1, t0n);
    BAR1(); MM(0, 1, bf23); BAR2();
    LDA(1, 1); STG(Bs, Bg, 1, 0, t1n);
    BAR1(); MM(1, 0, bf01); BAR2();
    STG(Bs, Bg, 1, 1, t1n);
    BAR1(); MM(1, 1, bf23); BAR2V();
  }
  asm volatile("s_waitcnt vmcnt(0)" ::: "memory");

#pragma unroll
  for (int i = 0; i < 8; ++i)
#pragma unroll
    for (int j = 0; j < 4; ++j)
#pragma unroll
      for (int r = 0; r < 4; ++r) {
        const int row = m0 + wm * 128 + i * 16 + lg * 4 + r;
        const int col = n0 + wn * 64 + j * 16 + lr;
        const float val = acc[i][j][r];
        if (OUTBF16) ((unsigned short*)Outp)[(size_t)row * N + col] = f2bf(val);
        else         ((float*)Outp)[(size_t)row * N + col] = val;
      }
}

// ---------------------------------------------------------------------------
// GEMM (m97 structure) + XCD swizzle — gemm3 (N=2048: 512 blocks).
// ---------------------------------------------------------------------------
template <bool OUTBF16>
__global__ __launch_bounds__(256, 2)
void gemm_bt16(const unsigned short* __restrict__ Ap, const unsigned short* __restrict__ Bp,
               void* __restrict__ Outp, int M, int N, int K)
{
  __shared__ __align__(16) char smA[128 * 128];
  __shared__ __align__(16) char smB[128 * 128];
  const int tid = threadIdx.x;
  const int wid = tid >> 6, lane = tid & 63;
  const int wr = wid >> 1, wc = wid & 1;
  const int lg = lane >> 4, lr = lane & 15;

  const int gx = gridDim.x;
  const int nwg = gx * gridDim.y;
  int bid = blockIdx.y * gx + blockIdx.x;
  bid = (bid & 7) * (nwg >> 3) + (bid >> 3);
  const int m0 = (bid / gx) * 128, n0 = (bid % gx) * 128;

  const int srow = wid * 8 + (lane >> 3);
  const int scol = (((lane & 7) ^ (lane >> 3)) << 3);
  const int lbase = wid * 1024;

  const f32x4 z4 = {0.f, 0.f, 0.f, 0.f};
  f32x4 acc[4][4];
#pragma unroll
  for (int i = 0; i < 4; ++i)
#pragma unroll
    for (int j = 0; j < 4; ++j) acc[i][j] = z4;

  for (int k0 = 0; k0 < K; k0 += 64) {
    __syncthreads();
#pragma unroll
    for (int c = 0; c < 4; ++c) {
      const int row = c * 32 + srow;
      gload16(Ap + (size_t)(m0 + row) * K + k0 + scol, smA + c * 4096 + lbase);
      gload16(Bp + (size_t)(n0 + row) * K + k0 + scol, smB + c * 4096 + lbase);
    }
    __syncthreads();
#pragma unroll
    for (int kk = 0; kk < 2; ++kk) {
      const int cb = (kk * 32 + lg * 8) * 2;
      bf16x8 a4[4], b4[4];
#pragma unroll
      for (int i = 0; i < 4; ++i) {
        const int row = wr * 64 + i * 16 + lr;
        a4[i] = *(const bf16x8*)(smA + row * 128 + (cb ^ ((row & 7) << 4)));
      }
#pragma unroll
      for (int j = 0; j < 4; ++j) {
        const int row = wc * 64 + j * 16 + lr;
        b4[j] = *(const bf16x8*)(smB + row * 128 + (cb ^ ((row & 7) << 4)));
      }
#pragma unroll
      for (int i = 0; i < 4; ++i)
#pragma unroll
        for (int j = 0; j < 4; ++j)
          acc[i][j] = __builtin_amdgcn_mfma_f32_16x16x32_bf16(a4[i], b4[j], acc[i][j], 0, 0, 0);
    }
  }
#pragma unroll
  for (int i = 0; i < 4; ++i)
#pragma unroll
    for (int j = 0; j < 4; ++j)
#pragma unroll
      for (int r = 0; r < 4; ++r) {
        const int row = m0 + wr * 64 + i * 16 + lg * 4 + r;
        const int col = n0 + wc * 64 + j * 16 + lr;
        const float val = acc[i][j][r];
        if (OUTBF16) ((unsigned short*)Outp)[(size_t)row * N + col] = f2bf(val);
        else         ((float*)Outp)[(size_t)row * N + col] = val;
      }
}

// ---------------------------------------------------------------------------
// V transpose: qkv V-part -> vT[(bh*128+d)*2048 + t]   (unchanged)
// ---------------------------------------------------------------------------
__global__ __launch_bounds__(256)
void vtrans(const unsigned short* __restrict__ qkv, unsigned short* __restrict__ vT)
{
  constexpr int T = 2048, ROWS = 6144;
  const int bh = blockIdx.y, b = bh >> 4, h = bh & 15;
  const int t0 = blockIdx.x * 64;
  const int tid = threadIdx.x;
  __shared__ __align__(16) char Sc[64 * 256];

#pragma unroll
  for (int c = 0; c < 4; ++c) {
    const int row = c * 16 + (tid >> 4);
    const int col = (tid & 15) * 8;
    u16x8 v = *(const u16x8*)(qkv + (size_t)(b * T + t0 + row) * ROWS + 4096 + h * 128 + col);
    *(u16x8*)(Sc + row * 256 + ((col * 2) ^ ((row & 7) << 4))) = v;
  }
  __syncthreads();
#pragma unroll
  for (int c = 0; c < 4; ++c) {
    const int d = c * 32 + (tid >> 3);
    const int t = (tid & 7) * 8;
    u16x8 v;
#pragma unroll
    for (int i = 0; i < 8; ++i)
      v[i] = *(const unsigned short*)(Sc + (t + i) * 256 + ((d * 2) ^ (((t + i) & 7) << 4)));
    *(u16x8*)(vT + ((size_t)bh * 128 + d) * 2048 + t0 + t) = v;
  }
}

// ---------------------------------------------------------------------------
// Flash attention v7: KVBLK=128 (one vmcnt/barrier stall per 128 keys),
// Ks[128][128d] + Vt[128d][128k] + Ps[64][128] = 80KB -> 2 blocks/CU.
// qt descending (heavy first); log2 softmax; T13 defer-max.
// ---------------------------------------------------------------------------
__global__ __launch_bounds__(256, 2)
void attn_fwd(const unsigned short* __restrict__ qkv, const unsigned short* __restrict__ vT,
              unsigned short* __restrict__ outp)
{
  constexpr int T = 2048, ROWS = 6144;
  const int blk = blockIdx.x;
  const int qt = 31 - (blk >> 5);       // heavy tiles first
  const int bh = blk & 31;
  const int b = bh >> 4, h = bh & 15;
  const int q0 = qt * 64;
  const int tid = threadIdx.x;
  const int wid = tid >> 6, lane = tid & 63;
  const int lg = lane >> 4, lr = lane & 15;

  __shared__ __align__(16) char Ks[128 * 256];  // 32KB [128 k][128 d] swizzled
  __shared__ __align__(16) char Vt[128 * 256];  // 32KB [128 d][128 k] swizzled
  __shared__ __align__(16) char Ps[64 * 256];   // 16KB [64 q][128 k] swizzled

  // staging coords (256B rows): round c covers rows c*16 + wid*4 + (lane>>4)
  const int srow = wid * 4 + (lane >> 4);
  const int scol = (((lane & 15) ^ (srow & 7)) << 3);   // c*16 doesn't affect &7

  const size_t qrow = (size_t)(b * T + q0 + wid * 16 + lr) * ROWS + h * 128;
  bf16x8 qf[4];
#pragma unroll
  for (int kd = 0; kd < 4; ++kd)
    qf[kd] = __builtin_bit_cast(bf16x8, *(const u16x8*)(qkv + qrow + kd * 32 + lg * 8));

  const f32x4 z4 = {0.f, 0.f, 0.f, 0.f};
  f32x4 oacc[8];
#pragma unroll
  for (int jj = 0; jj < 8; ++jj) oacc[jj] = z4;
  float mrow[4] = {-1e30f, -1e30f, -1e30f, -1e30f};
  float lsum[4] = {0.f, 0.f, 0.f, 0.f};
  const float scale2 = 0.12751745f;   // (1/sqrt(128)) * log2(e)

  const int nt = (qt >> 1) + 1;       // 128-key tiles (half-tile tail masked)
  for (int kt = 0; kt < nt; ++kt) {
    __syncthreads();
    // stage K tile [128k][128d] + V^T tile [128d][128k]
#pragma unroll
    for (int c = 0; c < 8; ++c) {
      gload16(qkv + (size_t)(b * T + kt * 128 + c * 16 + srow) * ROWS + 2048 + h * 128 + scol,
              Ks + c * 4096 + wid * 1024);
      gload16(vT + ((size_t)bh * 128 + c * 16 + srow) * 2048 + kt * 128 + scol,
              Vt + c * 4096 + wid * 1024);
    }
    asm volatile("s_waitcnt vmcnt(0)" ::: "memory");
    __syncthreads();

    // S = Q K^T  (8 col-frags = 128 keys)
    f32x4 sf[8];
#pragma unroll
    for (int j = 0; j < 8; ++j) sf[j] = z4;
#pragma unroll
    for (int kd = 0; kd < 4; ++kd) {
      const int cb = (kd * 32 + lg * 8) * 2;
#pragma unroll
      for (int j = 0; j < 8; ++j) {
        const int row = j * 16 + lr;
        bf16x8 kf = *(const bf16x8*)(Ks + row * 256 + (cb ^ ((row & 7) << 4)));
        sf[j] = __builtin_amdgcn_mfma_f32_16x16x32_bf16(qf[kd], kf, sf[j], 0, 0, 0);
      }
    }

    // softmax in log2 domain; mask only the last tile
    const bool diag = (kt == nt - 1);
#pragma unroll
    for (int j = 0; j < 8; ++j)
#pragma unroll
      for (int r = 0; r < 4; ++r) {
        float s = sf[j][r] * scale2;
        const int key = kt * 128 + j * 16 + lr;
        const int qi  = q0 + wid * 16 + lg * 4 + r;
        if (diag && key > qi) s = -1e30f;
        sf[j][r] = s;
      }
    float pm[4];
#pragma unroll
    for (int r = 0; r < 4; ++r) {
      float m0 = fmaxf(fmaxf(sf[0][r], sf[1][r]), fmaxf(sf[2][r], sf[3][r]));
      float m1 = fmaxf(fmaxf(sf[4][r], sf[5][r]), fmaxf(sf[6][r], sf[7][r]));
      pm[r] = red16max(fmaxf(m0, m1));
    }
    const float growth = fmaxf(fmaxf(pm[0] - mrow[0], pm[1] - mrow[1]),
                               fmaxf(pm[2] - mrow[2], pm[3] - mrow[3]));
    const bool resc = !__all(growth <= 11.5f);
    float alpha[4];
    if (resc) {
#pragma unroll
      for (int r = 0; r < 4; ++r) {
        const float mn = fmaxf(mrow[r], pm[r]);
        alpha[r] = exp2f(mrow[r] - mn);
        mrow[r] = mn;
      }
    }
    float rs[4] = {0.f, 0.f, 0.f, 0.f};
#pragma unroll
    for (int j = 0; j < 8; ++j)
#pragma unroll
      for (int r = 0; r < 4; ++r) {
        const float p = exp2f(sf[j][r] - mrow[r]);
        sf[j][r] = p;
        rs[r] += p;
      }
    if (resc) {
#pragma unroll
      for (int r = 0; r < 4; ++r) lsum[r] = lsum[r] * alpha[r] + red16sum(rs[r]);
    } else {
#pragma unroll
      for (int r = 0; r < 4; ++r) lsum[r] += red16sum(rs[r]);
    }

    // P -> Ps (wave-private rows, 256B rows)
#pragma unroll
    for (int j = 0; j < 8; ++j)
#pragma unroll
      for (int r = 0; r < 4; ++r) {
        const int prow = wid * 16 + lg * 4 + r;
        const int pcol = j * 16 + lr;
        *(unsigned short*)(Ps + prow * 256 + ((pcol * 2) ^ ((prow & 7) << 4))) = f2bf(sf[j][r]);
      }
    if (resc) {
#pragma unroll
      for (int jj = 0; jj < 8; ++jj)
#pragma unroll
        for (int r = 0; r < 4; ++r) oacc[jj][r] *= alpha[r];
    }
    asm volatile("s_waitcnt lgkmcnt(0)" ::: "memory");
    __builtin_amdgcn_sched_barrier(0);

    // O += P V  (4 k-blocks of 32)
#pragma unroll
    for (int kk = 0; kk < 4; ++kk) {
      const int prow = wid * 16 + lr;
      const int pcb = (kk * 32 + lg * 8) * 2;
      bf16x8 pf = *(const bf16x8*)(Ps + prow * 256 + (pcb ^ ((prow & 7) << 4)));
#pragma unroll
      for (int jj = 0; jj < 8; ++jj) {
        const int vrow = jj * 16 + lr;
        bf16x8 vf = *(const bf16x8*)(Vt + vrow * 256 + (pcb ^ ((vrow & 7) << 4)));
        oacc[jj] = __builtin_amdgcn_mfma_f32_16x16x32_bf16(pf, vf, oacc[jj], 0, 0, 0);
      }
    }
  }

  // epilogue
#pragma unroll
  for (int jj = 0; jj < 8; ++jj)
#pragma unroll
    for (int r = 0; r < 4; ++r) {
      const int q = q0 + wid * 16 + lg * 4 + r;
      const int col = h * 128 + jj * 16 + lr;
      const float o = oacc[jj][r] / lsum[r];
      outp[(size_t)(b * T + q) * 2048 + col] = f2bf(o);
    }
}

// ---------------------------------------------------------------------------
extern "C" void kernel_launch(void* const* d_in, const int* in_sizes, int n_in,
                              void* d_out, int out_size, void* d_ws, size_t ws_size,
                              hipStream_t stream) {
  (void)in_sizes; (void)n_in; (void)out_size; (void)ws_size;
  const float* x     = (const float*)d_in[0];   // [2,2048,2048]
  const float* qkvw  = (const float*)d_in[1];   // [6144,2048]
  const float* projw = (const float*)d_in[2];   // [2048,2048]

  unsigned short* qkvb   = (unsigned short*)d_ws;               // [4096][6144]
  unsigned short* attnb  = qkvb   + (size_t)4096 * 6144;        // [4096][2048]
  unsigned short* xb     = attnb  + (size_t)4096 * 2048;        // [4096][2048]
  unsigned short* qkvwb  = xb     + (size_t)4096 * 2048;        // [6144][2048]
  unsigned short* projwb = qkvwb  + (size_t)6144 * 2048;        // [2048][2048]
  unsigned short* vT     = xb;                                  // overlay (xb dead after gemm1)
  float* out = (float*)d_out;                                   // [4096][2048] f32

  static bool attr_set = false;
  if (!attr_set) {
    hipFuncSetAttribute((const void*)gemm256_bt<true>,
                        hipFuncAttributeMaxDynamicSharedMemorySize, 131072);
    attr_set = true;
  }

  cvt3_f32_bf16<<<4096 + 6144 + 2048, 256, 0, stream>>>(
      x, xb, 4096, qkvw, qkvwb, 6144, projw, projwb);
  gemm256_bt<true><<<dim3(6144 / 256, 4096 / 256), 512, 131072, stream>>>(
      xb, qkvwb, qkvb, 4096, 6144, 2048);
  vtrans<<<dim3(32, 32), 256, 0, stream>>>(qkvb, vT);
  attn_fwd<<<1024, 256, 0, stream>>>(qkvb, vT, attnb);
  gemm_bt16<false><<<dim3(2048 / 128, 4096 / 128), 256, 0, stream>>>(
      attnb, projwb, out, 4096, 2048, 2048);
}